// Round 13
// baseline (1065.098 us; speedup 1.0000x reference)
//
#include <hip/hip_runtime.h>

#define DEV __device__ __forceinline__

typedef __attribute__((ext_vector_type(8))) short short8;
typedef __attribute__((ext_vector_type(4))) float f32x4;
typedef unsigned short u16;

constexpr int kV = 80000, kD = 300, kNN = 32, kEE = 64, kHH = 4, kCC = 75;
constexpr int kB = 32, kT = 35, kU = 1024, kVG = 50000;
constexpr int kG = kB * kT;          // 1120
constexpr int kM = kG;

constexpr size_t alignup(size_t x) { return (x + 255) & ~size_t(255); }
constexpr size_t OFF_BAR   = 0;       // 256 flag slots (1024 B)
constexpr size_t OFF_WSRC  = 1024;
constexpr size_t OFF_WDST  = alignup(OFF_WSRC + 1200 * 4);
constexpr size_t OFF_BIAS  = alignup(OFF_WDST + 1200 * 4);
constexpr size_t OFF_SIG   = alignup(OFF_BIAS + 3 * 4096 * 4);
constexpr size_t OFF_WX0   = alignup(OFF_SIG + (size_t)35 * 32 * 640 * 2);
constexpr size_t OFF_WX12  = alignup(OFF_WX0 + (size_t)4096 * 640 * 2);
constexpr size_t OFF_GATES = alignup(OFF_WX12 + (size_t)2 * 4096 * 1024 * 2);
constexpr size_t OFF_HIST  = alignup(OFF_GATES + (size_t)1120 * 4096 * 4);
constexpr size_t OFF_PART  = alignup(OFF_HIST + (size_t)3 * 35 * 32 * 1024 * 2);
constexpr size_t OFF_LSE   = alignup(OFF_PART + (size_t)1120 * 784 * 8);
constexpr size_t OFF_LINWB = alignup(OFF_LSE + 1120 * 4);
constexpr size_t kLinWBytes = (size_t)kVG * 1024 * 2;
constexpr size_t kNeedBW   = OFF_LINWB + kLinWBytes;

DEV u16 f2bf(float f) {
  union { float f; unsigned u; } v; v.f = f;
  unsigned r = v.u + 0x7fffu + ((v.u >> 16) & 1u);
  return (u16)(r >> 16);
}
DEV float fexp(float x) { return __builtin_amdgcn_exp2f(x * 1.4426950408889634f); }
DEV float fsigm(float x) {
  float t = __builtin_amdgcn_exp2f(-1.4426950408889634f * x);
  return __builtin_amdgcn_rcpf(1.f + t);
}
DEV float ftanh(float x) {
  float xc = fminf(fmaxf(x, -20.f), 20.f);
  float t = __builtin_amdgcn_exp2f(2.8853900817779268f * xc);
  return (t - 1.f) * __builtin_amdgcn_rcpf(t + 1.f);
}
DEV f32x4 mfma16(short8 a, short8 b, f32x4 c) {
  return __builtin_amdgcn_mfma_f32_16x16x32_bf16(a, b, c, 0, 0, 0);
}
// store a bf16 directly to the coherent LLC (bypass non-coherent per-XCD L2).
DEV void store_u16_llc(u16* p, u16 v) {
  unsigned vv = v;
  asm volatile("global_store_short %0, %1, off sc0 sc1"
               :: "v"(p), "v"(vv) : "memory");
}
// async global->LDS DMA, 16B/lane, LDS dst = wave-uniform base + lane*16
DEV void gll16(const void* g, void* l) {
  __builtin_amdgcn_global_load_lds(
      (const __attribute__((address_space(1))) unsigned int*)g,
      (__attribute__((address_space(3))) unsigned int*)l, 16, 0, 0);
}

// ---------------- prep: ws_src/ws_dst (W @ att vectors), bias sums ----------
__global__ void prep_small(const float* __restrict__ gat_W,
                           const float* __restrict__ att_src,
                           const float* __restrict__ att_dst,
                           const float* __restrict__ b_ih,
                           const float* __restrict__ b_hh,
                           float* __restrict__ ws_src, float* __restrict__ ws_dst,
                           float* __restrict__ bias_sum) {
  int total = 1200 + 1200 + 3 * 4096;
  for (int i = blockIdx.x * blockDim.x + threadIdx.x; i < total; i += gridDim.x * blockDim.x) {
    if (i < 1200) {
      int d = i >> 2, h = i & 3;
      float s = 0.f;
      for (int c = 0; c < kCC; ++c) s += gat_W[d * 300 + h * kCC + c] * att_src[h * kCC + c];
      ws_src[i] = s;
    } else if (i < 2400) {
      int j = i - 1200; int d = j >> 2, h = j & 3;
      float s = 0.f;
      for (int c = 0; c < kCC; ++c) s += gat_W[d * 300 + h * kCC + c] * att_dst[h * kCC + c];
      ws_dst[j] = s;
    } else {
      int j = i - 2400;
      bias_sum[j] = b_ih[j] + b_hh[j];
    }
  }
}

// ---------------- prep: bf16 weights (W_ih0, layer-2 W_ih only) -------------
__global__ void wx_prep(const float* __restrict__ W_ih0,
                        const float* __restrict__ W_ih_rest,
                        u16* __restrict__ wx0, u16* __restrict__ wx12) {
  const int n0 = 4096 * 640;
  const int n2 = 4096 * 1024;       // layer-2 W_ih (W_ih_rest[1])
  int total = n0 + n2;
  for (int i = blockIdx.x * blockDim.x + threadIdx.x; i < total; i += gridDim.x * blockDim.x) {
    if (i < n0) {
      int row = i / 640, col = i - row * 640;
      float v = (col < 600) ? W_ih0[row * 600 + col] : 0.f;
      wx0[i] = f2bf(v);
    } else {
      int j = i - n0;
      wx12[(size_t)4096 * 1024 + j] = f2bf(W_ih_rest[(size_t)4096 * 1024 + j]);
    }
  }
}

// ---------------- prep: bf16 copy of lin_W ----------------------------------
__global__ void wb_conv(const float* __restrict__ W, u16* __restrict__ Wb) {
  const long n = (long)kVG * 1024;
  long stride = (long)gridDim.x * blockDim.x * 8;
  for (long i = (long)(blockIdx.x * blockDim.x + threadIdx.x) * 8; i < n; i += stride) {
    float4 a = *(const float4*)(W + i);
    float4 b = *(const float4*)(W + i + 4);
    u16 t[8] = {f2bf(a.x), f2bf(a.y), f2bf(a.z), f2bf(a.w),
                f2bf(b.x), f2bf(b.y), f2bf(b.z), f2bf(b.w)};
    *(uint4*)(Wb + i) = *(const uint4*)t;
  }
}

// ---------------- GAT (node-0 only, factored attention) ---------------------
__global__ void __launch_bounds__(256) gat_kernel(
    const int* __restrict__ x_indices, const int* __restrict__ edge_index,
    const float* __restrict__ X, const float* __restrict__ gat_W,
    const float* __restrict__ gat_bias, const float* __restrict__ ws_src,
    const float* __restrict__ ws_dst, u16* __restrict__ sig) {
  __shared__ float xs[32][301];
  __shared__ float a_s[32][4];
  __shared__ float a_d0[4];
  __shared__ float alpha[4][32];
  __shared__ float xw[4][301];
  __shared__ int allowed[32];
  int g = blockIdx.x, tid = threadIdx.x;
  const int* idx = x_indices + g * 32;
  for (int i = tid; i < 32 * 300; i += 256) {
    int j = i / 300, d2 = i - j * 300;
    xs[j][d2] = X[(size_t)idx[j] * 300 + d2];
  }
  if (tid < 32) allowed[tid] = (tid == 0) ? 1 : 0;
  __syncthreads();
  if (tid < 128) {
    int j = tid >> 2, h = tid & 3;
    float s = 0.f;
    for (int d2 = 0; d2 < 300; ++d2) s += xs[j][d2] * ws_src[d2 * 4 + h];
    a_s[j][h] = s;
  } else if (tid < 132) {
    int h = tid - 128; float s = 0.f;
    for (int d2 = 0; d2 < 300; ++d2) s += xs[0][d2] * ws_dst[d2 * 4 + h];
    a_d0[h] = s;
  } else if (tid >= 192) {
    int e = tid - 192;
    int src = edge_index[g * 128 + e];
    int dst = edge_index[g * 128 + 64 + e];
    if (dst == 0) allowed[src] = 1;
  }
  __syncthreads();
  if (tid < 4) {
    int h = tid;
    float ev[32];
    float mx = -1e30f;
    #pragma unroll
    for (int j = 0; j < 32; ++j) {
      float v = a_d0[h] + a_s[j][h];
      v = (v > 0.f) ? v : 0.2f * v;
      v = allowed[j] ? v : -1e9f;
      ev[j] = v; mx = fmaxf(mx, v);
    }
    float ssum = 0.f;
    #pragma unroll
    for (int j = 0; j < 32; ++j) { float p = fexp(ev[j] - mx); ev[j] = p; ssum += p; }
    float inv = 1.f / ssum;
    #pragma unroll
    for (int j = 0; j < 32; ++j) alpha[h][j] = ev[j] * inv;
  }
  __syncthreads();
  for (int i = tid; i < 4 * 300; i += 256) {
    int h = i / 300, d2 = i - h * 300;
    float s = 0.f;
    #pragma unroll
    for (int j = 0; j < 32; ++j) s += alpha[h][j] * xs[j][d2];
    xw[h][d2] = s;
  }
  __syncthreads();
  int t = g % 35, b = g / 35;
  u16* srow = sig + ((size_t)t * 32 + b) * 640;
  for (int hc = tid; hc < 300; hc += 256) {
    srow[hc] = f2bf(xs[0][hc]);           // curr_emb = X[idx 0]
    int h = hc / 75;
    float s = gat_bias[hc];
    for (int d2 = 0; d2 < 300; ++d2) s += xw[h][d2] * gat_W[d2 * 300 + hc];
    srow[300 + hc] = f2bf(s);
  }
  for (int i2 = 600 + tid; i2 < 640; i2 += 256) srow[i2] = 0;  // zero pad
}

// ---------------- bulk input-gate GEMM (gll16 dbuf + swizzled LDS) ----------
// gates written INTERLEAVED: gates[m][u*4+g]  (one float4 per (m,unit))
__global__ void __launch_bounds__(256, 4) gemm_ig(
    const u16* __restrict__ A, const u16* __restrict__ Bw,
    float* __restrict__ gates, int K) {
  int bid = blockIdx.x;
  int bm = bid % 9, bn = bid / 9;
  int m0 = bm * 128, n0 = bn * 128;
  int tid = threadIdx.x, w = tid >> 6, lane = tid & 63, l15 = lane & 15, lhi = lane >> 4;
  int wm = w & 1, wn = w >> 1;
  __shared__ u16 As[2][128][32];
  __shared__ u16 Bs[2][128][32];
  int cl = ((lane & 3) ^ ((lane >> 3) & 3)) * 8;
  int am0 = m0 + w * 32 + (lane >> 2);
  int am1 = am0 + 16;
  const u16* arow0 = A + (size_t)((am0 < kM) ? am0 : 0) * K + cl;
  const u16* arow1 = A + (size_t)((am1 < kM) ? am1 : 0) * K + cl;
  int bn0r = n0 + w * 32 + (lane >> 2);
  const u16* brow0 = Bw + (size_t)bn0r * K + cl;
  const u16* brow1 = Bw + (size_t)(bn0r + 16) * K + cl;
  const int koff = (lhi ^ ((l15 >> 1) & 3)) * 8;  // read-side swizzle

  f32x4 acc[4][4];
  #pragma unroll
  for (int i = 0; i < 4; ++i)
    #pragma unroll
    for (int j = 0; j < 4; ++j) { f32x4 z = {0.f, 0.f, 0.f, 0.f}; acc[i][j] = z; }

  auto ISSUE = [&](int k0, int buf) {
    gll16(arow0 + k0, &As[buf][w * 32][0]);
    gll16(arow1 + k0, &As[buf][w * 32 + 16][0]);
    gll16(brow0 + k0, &Bs[buf][w * 32][0]);
    gll16(brow1 + k0, &Bs[buf][w * 32 + 16][0]);
  };
  int nkt = K >> 5;
  ISSUE(0, 0);
  for (int kt = 0; kt < nkt; ++kt) {
    int cur = kt & 1;
    if (kt < nkt - 1) {
      ISSUE((kt + 1) * 32, cur ^ 1);
      asm volatile("s_waitcnt vmcnt(4)" ::: "memory");
    } else {
      asm volatile("s_waitcnt vmcnt(0)" ::: "memory");
    }
    __builtin_amdgcn_s_barrier();
    __builtin_amdgcn_sched_barrier(0);
    short8 bfr[4];
    #pragma unroll
    for (int nt = 0; nt < 4; ++nt)
      bfr[nt] = *(const short8*)&Bs[cur][wn * 64 + nt * 16 + l15][koff];
    #pragma unroll
    for (int mt = 0; mt < 4; ++mt) {
      short8 af = *(const short8*)&As[cur][wm * 64 + mt * 16 + l15][koff];
      #pragma unroll
      for (int nt = 0; nt < 4; ++nt)
        acc[mt][nt] = mfma16(af, bfr[nt], acc[mt][nt]);
    }
    __builtin_amdgcn_sched_barrier(0);
    __builtin_amdgcn_s_barrier();
  }
  #pragma unroll
  for (int mt = 0; mt < 4; ++mt) {
    #pragma unroll
    for (int r = 0; r < 4; ++r) {
      int m = m0 + wm * 64 + mt * 16 + lhi * 4 + r;
      if (m < kM) {
        float* orow = gates + (size_t)m * 4096;
        #pragma unroll
        for (int nt = 0; nt < 4; ++nt) {
          int n = n0 + wn * 64 + nt * 16 + l15;
          orow[(n & 1023) * 4 + (n >> 10)] = acc[mt][nt][r];
        }
      }
    }
  }
}

// ---------------- fused layers 0+1 LSTM wavefront (dataflow flags) ----------
// 256 blocks, block p owns units [4p,4p+4) for BOTH layers. 36 supersteps:
// layer0 computes t=s, layer1 computes t=s-1 (x-part inline vs h0).
// All weights (Whh0, Whh1, Wih1) LDS-resident bf16. Wave w K-slice [256w,+256)
// waits only on its 64 producer blocks.
__global__ void __launch_bounds__(256, 1) lstm_fused01(
    const float* __restrict__ W_hh,      // [3][4096][1024]
    const float* __restrict__ W_ih_rest, // [2][4096][1024]; [0] = layer1
    const float* __restrict__ gates,     // [1120][1024][4] f32 (layer0 x-part)
    const float* __restrict__ bias_sum,  // [3][4096]
    u16* __restrict__ hist0, u16* __restrict__ hist1,
    unsigned* __restrict__ flags) {
  const int p = blockIdx.x;            // 0..255
  const int u0 = p * 4;
  const int tid = threadIdx.x;
  const int w = tid >> 6, lane = tid & 63, l15 = lane & 15, lhi = lane >> 4;
  __shared__ u16 wh0[16][1032];
  __shared__ u16 wh1[16][1032];
  __shared__ u16 wi1[16][1032];
  __shared__ float pred0[4][16][33];
  __shared__ float pred1[4][16][33];

  // prologue: convert fp32 weight rows -> bf16 LDS. row = g*4+j.
  for (int i = tid; i < 16 * 256; i += 256) {
    int row = i >> 8, seg = (i & 255) * 4;
    int g = row >> 2, j = row & 3;
    size_t grow = (size_t)(g * 1024 + u0 + j) * 1024 + seg;
    float4 f0 = *(const float4*)(W_hh + grow);
    u16 t0[4] = {f2bf(f0.x), f2bf(f0.y), f2bf(f0.z), f2bf(f0.w)};
    *(uint2*)&wh0[row][seg] = *(const uint2*)t0;
    float4 f1 = *(const float4*)(W_hh + (size_t)4096 * 1024 + grow);
    u16 t1[4] = {f2bf(f1.x), f2bf(f1.y), f2bf(f1.z), f2bf(f1.w)};
    *(uint2*)&wh1[row][seg] = *(const uint2*)t1;
    float4 f2 = *(const float4*)(W_ih_rest + grow);
    u16 t2[4] = {f2bf(f2.x), f2bf(f2.y), f2bf(f2.z), f2bf(f2.w)};
    *(uint2*)&wi1[row][seg] = *(const uint2*)t2;
  }

  const int half = tid >> 7;           // 0: layer0 pointwise, 1: layer1
  const int pb = (tid & 127) >> 2;     // batch 0..31
  const int pj = tid & 3;              // local unit 0..3
  float bias_r[4];
  #pragma unroll
  for (int g = 0; g < 4; ++g)
    bias_r[g] = bias_sum[half * 4096 + g * 1024 + u0 + pj];
  float c_reg = 0.f;
  const int kbase = w * 256;
  const unsigned* myflag = flags + w * 64 + lane;  // wave's 64 producers
  __syncthreads();

  for (int s = 0; s < 36; ++s) {
    const bool l0act = s < 35;
    const bool l1act = s >= 1;
    if (s >= 1) {
      unsigned tgt = (unsigned)s;
      while (!__all((int)(__hip_atomic_load(myflag, __ATOMIC_RELAXED,
                                            __HIP_MEMORY_SCOPE_AGENT) >= tgt)))
        __builtin_amdgcn_s_sleep(1);
      asm volatile("" ::: "memory");   // pin h loads behind the wait
    }
    f32x4 a00 = {0,0,0,0}, a01 = {0,0,0,0};
    f32x4 a10 = {0,0,0,0}, a11 = {0,0,0,0};
    if (l0act && s >= 1) {             // layer0 h-part: B = h0[s-1]
      const u16* hp = hist0 + (size_t)(s - 1) * 32 * 1024;
      const u16* h0p = hp + l15 * 1024 + lhi * 8;
      const u16* h1p = hp + (l15 + 16) * 1024 + lhi * 8;
      #pragma unroll
      for (int kk = 0; kk < 8; ++kk) {
        int k = kbase + kk * 32;
        short8 af = *(const short8*)&wh0[l15][k + lhi * 8];
        short8 b0 = *(const short8*)(h0p + k);
        short8 b1 = *(const short8*)(h1p + k);
        a00 = mfma16(af, b0, a00);
        a01 = mfma16(af, b1, a01);
      }
    }
    if (l1act) {                       // layer1 x-part: B = h0[s-1]
      const u16* xp = hist0 + (size_t)(s - 1) * 32 * 1024;
      const u16* x0p = xp + l15 * 1024 + lhi * 8;
      const u16* x1p = xp + (l15 + 16) * 1024 + lhi * 8;
      #pragma unroll
      for (int kk = 0; kk < 8; ++kk) {
        int k = kbase + kk * 32;
        short8 af = *(const short8*)&wi1[l15][k + lhi * 8];
        short8 b0 = *(const short8*)(x0p + k);
        short8 b1 = *(const short8*)(x1p + k);
        a10 = mfma16(af, b0, a10);
        a11 = mfma16(af, b1, a11);
      }
      if (s >= 2) {                    // layer1 h-part: B = h1[s-2]
        const u16* hp = hist1 + (size_t)(s - 2) * 32 * 1024;
        const u16* h0p = hp + l15 * 1024 + lhi * 8;
        const u16* h1p = hp + (l15 + 16) * 1024 + lhi * 8;
        #pragma unroll
        for (int kk = 0; kk < 8; ++kk) {
          int k = kbase + kk * 32;
          short8 af = *(const short8*)&wh1[l15][k + lhi * 8];
          short8 b0 = *(const short8*)(h0p + k);
          short8 b1 = *(const short8*)(h1p + k);
          a10 = mfma16(af, b0, a10);
          a11 = mfma16(af, b1, a11);
        }
      }
    }
    #pragma unroll
    for (int r = 0; r < 4; ++r) {
      pred0[w][lhi * 4 + r][l15]      = a00[r];
      pred0[w][lhi * 4 + r][l15 + 16] = a01[r];
      pred1[w][lhi * 4 + r][l15]      = a10[r];
      pred1[w][lhi * 4 + r][l15 + 16] = a11[r];
    }
    __syncthreads();
    if (half == 0) {
      if (l0act) {
        int t0 = s;
        float4 gx = ((const float4*)gates)[(size_t)(t0 * 32 + pb) * 1024 + u0 + pj];
        float pre[4];
        #pragma unroll
        for (int g = 0; g < 4; ++g) {
          int row = g * 4 + pj;
          pre[g] = pred0[0][row][pb] + pred0[1][row][pb] +
                   pred0[2][row][pb] + pred0[3][row][pb];
        }
        float iv = gx.x + pre[0] + bias_r[0];
        float fv = gx.y + pre[1] + bias_r[1];
        float gv = gx.z + pre[2] + bias_r[2];
        float ov = gx.w + pre[3] + bias_r[3];
        float cc = fsigm(fv) * c_reg + fsigm(iv) * ftanh(gv);
        float hh = fsigm(ov) * ftanh(cc);
        c_reg = cc;
        store_u16_llc(hist0 + ((size_t)(t0 * 32 + pb) << 10) + u0 + pj, f2bf(hh));
      }
    } else {
      if (l1act) {
        int t1 = s - 1;
        float pre[4];
        #pragma unroll
        for (int g = 0; g < 4; ++g) {
          int row = g * 4 + pj;
          pre[g] = pred1[0][row][pb] + pred1[1][row][pb] +
                   pred1[2][row][pb] + pred1[3][row][pb];
        }
        float iv = pre[0] + bias_r[0];
        float fv = pre[1] + bias_r[1];
        float gv = pre[2] + bias_r[2];
        float ov = pre[3] + bias_r[3];
        float cc = fsigm(fv) * c_reg + fsigm(iv) * ftanh(gv);
        float hh = fsigm(ov) * ftanh(cc);
        c_reg = cc;
        store_u16_llc(hist1 + ((size_t)(t1 * 32 + pb) << 10) + u0 + pj, f2bf(hh));
      }
    }
    __syncthreads();   // all waves' LLC stores drained (vmcnt 0 at barrier)
    if (s < 35 && tid == 0)
      __hip_atomic_store(flags + p, (unsigned)(s + 1),
                         __ATOMIC_RELAXED, __HIP_MEMORY_SCOPE_AGENT);
  }
}

// ---------------- LSTM recurrence layer 2 (dataflow flags) ------------------
__global__ void __launch_bounds__(256, 1) lstm_rec(
    const float* __restrict__ W_hh_l,   // [4096][1024] fp32, this layer
    const float* __restrict__ gates,    // [1120][1024][4] f32 interleaved
    const float* __restrict__ bias_l,   // [4096]
    u16* __restrict__ hout,             // [35*32][1024] bf16
    unsigned* flags, unsigned sbase) {
  const int p = blockIdx.x;             // 0..127
  const int tid = threadIdx.x;
  const int w = tid >> 6, lane = tid & 63, l15 = lane & 15, lhi = lane >> 4;
  __shared__ u16 whs[32][1032];         // rows: idx = g*8+jj
  __shared__ float pred[4][32][33];     // [wave][w-row][batch]
  for (int i = tid; i < 32 * 256; i += 256) {
    int row = i >> 8, seg = i & 255;
    int g = row >> 3, jj = row & 7;
    const float* src = W_hh_l + (((size_t)(g * 1024 + p * 8 + jj)) << 10) + seg * 4;
    float4 f = *(const float4*)src;
    u16 tmp[4] = {f2bf(f.x), f2bf(f.y), f2bf(f.z), f2bf(f.w)};
    *(uint2*)&whs[row][seg * 4] = *(const uint2*)tmp;
  }
  const int bb = tid >> 3, jj2 = tid & 7;
  float bias_r[4];
  #pragma unroll
  for (int g = 0; g < 4; ++g) bias_r[g] = bias_l[g * 1024 + p * 8 + jj2];
  float c_reg = 0.f;
  const int kbase = w * 256;
  const float4* gb4 = (const float4*)gates + (size_t)bb * 1024 + (p * 8 + jj2);
  const unsigned* myflags = flags + w * 32 + (lane & 31);

  float4 gx = gb4[0];
  __syncthreads();

  for (int t = 0; t < 35; ++t) {
    float4 gxn;
    if (t > 0) {
      unsigned tgt = sbase + (unsigned)t;
      while (!__all((int)(__hip_atomic_load(myflags, __ATOMIC_RELAXED,
                                            __HIP_MEMORY_SCOPE_AGENT) >= tgt)))
        __builtin_amdgcn_s_sleep(1);
      asm volatile("" ::: "memory");
      const u16* hp = hout + (size_t)(t - 1) * 32 * 1024;
      const u16* hrow0 = hp + l15 * 1024 + lhi * 8;
      const u16* hrow1 = hp + (l15 + 16) * 1024 + lhi * 8;
      f32x4 acc00 = {0,0,0,0}, acc01 = {0,0,0,0}, acc10 = {0,0,0,0}, acc11 = {0,0,0,0};
      #pragma unroll
      for (int kk = 0; kk < 8; ++kk) {
        int k = kbase + kk * 32;
        short8 bf0 = *(const short8*)(hrow0 + k);
        short8 bf1 = *(const short8*)(hrow1 + k);
        short8 af0 = *(const short8*)&whs[l15][k + lhi * 8];
        short8 af1 = *(const short8*)&whs[16 + l15][k + lhi * 8];
        acc00 = mfma16(af0, bf0, acc00);
        acc01 = mfma16(af0, bf1, acc01);
        acc10 = mfma16(af1, bf0, acc10);
        acc11 = mfma16(af1, bf1, acc11);
      }
      if (t < 34) gxn = gb4[(size_t)(t + 1) * 32768];
      #pragma unroll
      for (int r = 0; r < 4; ++r) {
        pred[w][lhi * 4 + r][l15]       = acc00[r];
        pred[w][lhi * 4 + r][l15 + 16]  = acc01[r];
        pred[w][16 + lhi * 4 + r][l15]      = acc10[r];
        pred[w][16 + lhi * 4 + r][l15 + 16] = acc11[r];
      }
      __syncthreads();
    } else {
      gxn = gb4[(size_t)32 * 1024];
    }
    float pre[4];
    #pragma unroll
    for (int g = 0; g < 4; ++g) {
      float s = 0.f;
      if (t > 0) {
        int row = g * 8 + jj2;
        s = pred[0][row][bb] + pred[1][row][bb] + pred[2][row][bb] + pred[3][row][bb];
      }
      pre[g] = s;
    }
    float iv = gx.x + pre[0] + bias_r[0];
    float fv = gx.y + pre[1] + bias_r[1];
    float gv = gx.z + pre[2] + bias_r[2];
    float ov = gx.w + pre[3] + bias_r[3];
    float cc = fsigm(fv) * c_reg + fsigm(iv) * ftanh(gv);
    float hh = fsigm(ov) * ftanh(cc);
    c_reg = cc;
    store_u16_llc(hout + ((size_t)(t * 32 + bb)) * 1024 + p * 8 + jj2, f2bf(hh));
    __syncthreads();
    if (t < 34 && tid == 0)
      __hip_atomic_store(flags + p, sbase + (unsigned)t + 1u,
                         __ATOMIC_RELAXED, __HIP_MEMORY_SCOPE_AGENT);
    gx = gxn;
  }
}

// ---------------- logits GEMM epilogue --------------------------------------
DEV void logits_epilogue(f32x4 (&acc)[4][4], int m0, int n0, int wm, int wn,
                         int l15, int lhi, const float* lin_b,
                         float* out, float2* partials, int bn) {
  float bcol[4]; int ncol[4];
  #pragma unroll
  for (int nt = 0; nt < 4; ++nt) {
    int n = n0 + wn * 64 + nt * 16 + l15;
    ncol[nt] = n;
    bcol[nt] = (n < kVG) ? lin_b[n] : -INFINITY;
  }
  #pragma unroll
  for (int mt = 0; mt < 4; ++mt) {
    #pragma unroll
    for (int r = 0; r < 4; ++r) {
      int m = m0 + wm * 64 + mt * 16 + lhi * 4 + r;
      float v0 = acc[mt][0][r] + bcol[0];
      float v1 = acc[mt][1][r] + bcol[1];
      float v2 = acc[mt][2][r] + bcol[2];
      float v3 = acc[mt][3][r] + bcol[3];
      bool mok = (m < kM);
      if (mok) {
        float* orow = out + (size_t)m * kVG;
        if (ncol[0] < kVG) orow[ncol[0]] = v0;
        if (ncol[1] < kVG) orow[ncol[1]] = v1;
        if (ncol[2] < kVG) orow[ncol[2]] = v2;
        if (ncol[3] < kVG) orow[ncol[3]] = v3;
      }
      float mx = fmaxf(fmaxf(v0, v1), fmaxf(v2, v3));
      #pragma unroll
      for (int d2 = 1; d2 < 16; d2 <<= 1) mx = fmaxf(mx, __shfl_xor(mx, d2, 64));
      float sv = 0.f;
      sv += (v0 > -1e30f) ? fexp(v0 - mx) : 0.f;
      sv += (v1 > -1e30f) ? fexp(v1 - mx) : 0.f;
      sv += (v2 > -1e30f) ? fexp(v2 - mx) : 0.f;
      sv += (v3 > -1e30f) ? fexp(v3 - mx) : 0.f;
      #pragma unroll
      for (int d2 = 1; d2 < 16; d2 <<= 1) sv += __shfl_xor(sv, d2, 64);
      if (mok && l15 == 0)
        partials[(size_t)m * 784 + bn * 2 + wn] = make_float2(mx, sv);
    }
  }
}

// ---------------- logits GEMM (gll16 dbuf + swizzled LDS) -------------------
__global__ void __launch_bounds__(256, 4) gemm_logits_async(
    const u16* __restrict__ hist2, const u16* __restrict__ linwb,
    const float* __restrict__ lin_b, float* __restrict__ out,
    float2* __restrict__ partials) {
  int nwg = gridDim.x, orig = blockIdx.x;
  int q = nwg >> 3, r = nwg & 7, xcd = orig & 7, off = orig >> 3;
  int bid = (xcd < r ? xcd * (q + 1) : r * (q + 1) + (xcd - r) * q) + off;
  int bm = bid % 9, bn = bid / 9;
  int m0 = bm * 128, n0 = bn * 128;
  int tid = threadIdx.x, w = tid >> 6, lane = tid & 63, l15 = lane & 15, lhi = lane >> 4;
  int wm = w & 1, wn = w >> 1;
  __shared__ u16 As[2][128][32];
  __shared__ u16 Bs[2][128][32];
  int cl = ((lane & 3) ^ ((lane >> 3) & 3)) * 8;
  int am0 = m0 + w * 32 + (lane >> 2);
  int am1 = am0 + 16;
  int mm0 = (am0 < kM) ? am0 : 0, mm1 = (am1 < kM) ? am1 : 0;
  const u16* arow0 = hist2 + (((size_t)((mm0 % 35) * 32 + mm0 / 35)) << 10) + cl;
  const u16* arow1 = hist2 + (((size_t)((mm1 % 35) * 32 + mm1 / 35)) << 10) + cl;
  int nr0 = n0 + w * 32 + (lane >> 2);
  int nn0 = (nr0 < kVG) ? nr0 : 0, nn1 = (nr0 + 16 < kVG) ? nr0 + 16 : 0;
  const u16* brow0 = linwb + ((size_t)nn0 << 10) + cl;
  const u16* brow1 = linwb + ((size_t)nn1 << 10) + cl;
  const int koff = (lhi ^ ((l15 >> 1) & 3)) * 8;

  f32x4 acc[4][4];
  #pragma unroll
  for (int i = 0; i < 4; ++i)
    #pragma unroll
    for (int j = 0; j < 4; ++j) { f32x4 z = {0.f, 0.f, 0.f, 0.f}; acc[i][j] = z; }

  auto ISSUE = [&](int k0, int buf) {
    gll16(arow0 + k0, &As[buf][w * 32][0]);
    gll16(arow1 + k0, &As[buf][w * 32 + 16][0]);
    gll16(brow0 + k0, &Bs[buf][w * 32][0]);
    gll16(brow1 + k0, &Bs[buf][w * 32 + 16][0]);
  };
  ISSUE(0, 0);
  for (int kt = 0; kt < 32; ++kt) {
    int cur = kt & 1;
    if (kt < 31) {
      ISSUE((kt + 1) * 32, cur ^ 1);
      asm volatile("s_waitcnt vmcnt(4)" ::: "memory");
    } else {
      asm volatile("s_waitcnt vmcnt(0)" ::: "memory");
    }
    __builtin_amdgcn_s_barrier();
    __builtin_amdgcn_sched_barrier(0);
    short8 bfr[4];
    #pragma unroll
    for (int nt = 0; nt < 4; ++nt)
      bfr[nt] = *(const short8*)&Bs[cur][wn * 64 + nt * 16 + l15][koff];
    #pragma unroll
    for (int mt = 0; mt < 4; ++mt) {
      short8 af = *(const short8*)&As[cur][wm * 64 + mt * 16 + l15][koff];
      #pragma unroll
      for (int nt = 0; nt < 4; ++nt)
        acc[mt][nt] = mfma16(af, bfr[nt], acc[mt][nt]);
    }
    __builtin_amdgcn_sched_barrier(0);
    __builtin_amdgcn_s_barrier();
  }
  logits_epilogue(acc, m0, n0, wm, wn, l15, lhi, lin_b, out, partials, bn);
}

// fallback (no bf16 workspace image): reg-staged, fp32 B inline-converted
__global__ void __launch_bounds__(256, 1) gemm_logits_fb(
    const u16* __restrict__ hist2, const float* __restrict__ lin_W,
    const float* __restrict__ lin_b, float* __restrict__ out,
    float2* __restrict__ partials) {
  int nwg = gridDim.x, orig = blockIdx.x;
  int q = nwg >> 3, r = nwg & 7, xcd = orig & 7, off = orig >> 3;
  int bid = (xcd < r ? xcd * (q + 1) : r * (q + 1) + (xcd - r) * q) + off;
  int bm = bid % 9, bn = bid / 9;
  int m0 = bm * 128, n0 = bn * 128;
  int tid = threadIdx.x, w = tid >> 6, lane = tid & 63, l15 = lane & 15, lhi = lane >> 4;
  int wm = w & 1, wn = w >> 1;
  __shared__ u16 As[128][40];
  __shared__ u16 Bs[128][40];
  f32x4 acc[4][4];
  #pragma unroll
  for (int i = 0; i < 4; ++i)
    #pragma unroll
    for (int j = 0; j < 4; ++j) { f32x4 z = {0.f, 0.f, 0.f, 0.f}; acc[i][j] = z; }
  for (int kt = 0; kt < 32; ++kt) {
    int k0 = kt * 32;
    #pragma unroll
    for (int q2 = 0; q2 < 2; ++q2) {
      int c = tid * 2 + q2; int row = c >> 2; int ch = c & 3;
      int m = m0 + row;
      uint4 av{0u, 0u, 0u, 0u};
      if (m < kM) {
        int b = m / 35; int t = m - b * 35;
        av = *(const uint4*)(hist2 + ((size_t)(t * 32 + b) << 10) + k0 + ch * 8);
      }
      *(uint4*)&As[row][ch * 8] = av;
      int n = n0 + row;
      uint4 bv{0u, 0u, 0u, 0u};
      if (n < kVG) {
        const float* src = lin_W + (size_t)n * 1024 + k0 + ch * 8;
        float4 f0 = *(const float4*)(src);
        float4 f1 = *(const float4*)(src + 4);
        bv.x = (unsigned)f2bf(f0.x) | ((unsigned)f2bf(f0.y) << 16);
        bv.y = (unsigned)f2bf(f0.z) | ((unsigned)f2bf(f0.w) << 16);
        bv.z = (unsigned)f2bf(f1.x) | ((unsigned)f2bf(f1.y) << 16);
        bv.w = (unsigned)f2bf(f1.z) | ((unsigned)f2bf(f1.w) << 16);
      }
      *(uint4*)&Bs[row][ch * 8] = bv;
    }
    __syncthreads();
    short8 bfr[4];
    #pragma unroll
    for (int nt = 0; nt < 4; ++nt)
      bfr[nt] = *(const short8*)&Bs[wn * 64 + nt * 16 + l15][lhi * 8];
    #pragma unroll
    for (int mt = 0; mt < 4; ++mt) {
      short8 af = *(const short8*)&As[wm * 64 + mt * 16 + l15][lhi * 8];
      #pragma unroll
      for (int nt = 0; nt < 4; ++nt)
        acc[mt][nt] = mfma16(af, bfr[nt], acc[mt][nt]);
    }
    __syncthreads();
  }
  logits_epilogue(acc, m0, n0, wm, wn, l15, lhi, lin_b, out, partials, bn);
}

// ---------------- row logsumexp reduce --------------------------------------
__global__ void reduce_rows(const float2* __restrict__ partials, float* __restrict__ lse) {
  int m = blockIdx.x, tid = threadIdx.x;
  float mx = -INFINITY, s = 0.f;
  for (int j = tid; j < 782; j += 256) {
    float2 p = partials[(size_t)m * 784 + j];
    if (p.x > mx) { s = s * fexp(mx - p.x) + p.y; mx = p.x; }
    else          { s += p.y * fexp(p.x - mx); }
  }
  for (int d = 1; d < 64; d <<= 1) {
    float omx = __shfl_xor(mx, d, 64);
    float os  = __shfl_xor(s, d, 64);
    if (omx > mx) { s = s * fexp(mx - omx) + os; mx = omx; }
    else          { s += os * fexp(omx - mx); }
  }
  __shared__ float smx[4], ssum[4];
  int w = tid >> 6;
  if ((tid & 63) == 0) { smx[w] = mx; ssum[w] = s; }
  __syncthreads();
  if (tid == 0) {
    for (int i = 1; i < 4; ++i) {
      float omx = smx[i], os = ssum[i];
      if (omx > mx) { s = s * fexp(mx - omx) + os; mx = omx; }
      else          { s += os * fexp(omx - mx); }
    }
    lse[m] = mx + logf(s);
  }
}

// ---------------- in-place log_softmax subtract -----------------------------
__global__ void sub_lse(float* __restrict__ out, const float* __restrict__ lse) {
  const int total4 = 14000000;  // 1120*50000/4
  for (int i = blockIdx.x * blockDim.x + threadIdx.x; i < total4; i += gridDim.x * blockDim.x) {
    int m = i / 12500;
    float4 v = ((float4*)out)[i];
    float L = lse[m];
    v.x -= L; v.y -= L; v.z -= L; v.w -= L;
    ((float4*)out)[i] = v;
  }
}

// ---------------- launch ----------------------------------------------------
extern "C" void kernel_launch(void* const* d_in, const int* in_sizes, int n_in,
                              void* d_out, int out_size, void* d_ws, size_t ws_size,
                              hipStream_t stream) {
  const int*   x_indices  = (const int*)d_in[0];
  const int*   edge_index = (const int*)d_in[1];
  const float* X          = (const float*)d_in[2];
  const float* gat_W      = (const float*)d_in[3];
  const float* att_src    = (const float*)d_in[4];
  const float* att_dst    = (const float*)d_in[5];
  const float* gat_bias   = (const float*)d_in[6];
  const float* W_ih0      = (const float*)d_in[7];
  const float* W_ih_rest  = (const float*)d_in[8];
  const float* W_hh       = (const float*)d_in[9];
  const float* b_ih       = (const float*)d_in[10];
  const float* b_hh       = (const float*)d_in[11];
  const float* lin_W      = (const float*)d_in[12];
  const float* lin_b      = (const float*)d_in[13];
  float* out = (float*)d_out;
  char* ws = (char*)d_ws;

  unsigned* flags    = (unsigned*)(ws + OFF_BAR);
  float*    ws_src   = (float*)(ws + OFF_WSRC);
  float*    ws_dst   = (float*)(ws + OFF_WDST);
  float*    bias_sum = (float*)(ws + OFF_BIAS);
  u16*      sig      = (u16*)(ws + OFF_SIG);
  u16*      wx0      = (u16*)(ws + OFF_WX0);
  u16*      wx12     = (u16*)(ws + OFF_WX12);
  float*    gates    = (float*)(ws + OFF_GATES);
  u16*      hist     = (u16*)(ws + OFF_HIST);
  float2*   partials = (float2*)(ws + OFF_PART);
  float*    lse      = (float*)(ws + OFF_LSE);
  u16*      linwb    = (u16*)(ws + OFF_LINWB);
  bool use_bw = (ws_size >= kNeedBW);

  u16* hist0 = hist;
  u16* hist1 = hist + (size_t)35 * 32 * 1024;
  u16* hist2 = hist + (size_t)2 * 35 * 32 * 1024;

  hipMemsetAsync(ws + OFF_BAR, 0, 1024, stream);
  prep_small<<<64, 256, 0, stream>>>(gat_W, att_src, att_dst, b_ih, b_hh,
                                     ws_src, ws_dst, bias_sum);
  wx_prep<<<1024, 256, 0, stream>>>(W_ih0, W_ih_rest, wx0, wx12);
  if (use_bw) wb_conv<<<2048, 256, 0, stream>>>(lin_W, linwb);
  gat_kernel<<<kG, 256, 0, stream>>>(x_indices, edge_index, X, gat_W, gat_bias,
                                     ws_src, ws_dst, sig);
  // layer 0 input transform (bulk)
  gemm_ig<<<288, 256, 0, stream>>>(sig, wx0, gates, 640);
  // fused layers 0+1 wavefront (36 supersteps, dataflow flags)
  lstm_fused01<<<256, 256, 0, stream>>>(W_hh, W_ih_rest, gates, bias_sum,
                                        hist0, hist1, flags);
  // layer 2
  gemm_ig<<<288, 256, 0, stream>>>(hist1, wx12 + (size_t)4096 * 1024, gates, 1024);
  lstm_rec<<<128, 256, 0, stream>>>(W_hh + (size_t)2 * 4096 * 1024, gates,
                                    bias_sum + 8192, hist2, flags, 64u);
  // logits + log_softmax
  if (use_bw)
    gemm_logits_async<<<9 * 391, 256, 0, stream>>>(hist2, linwb, lin_b, out, partials);
  else
    gemm_logits_fb<<<9 * 391, 256, 0, stream>>>(hist2, lin_W, lin_b, out, partials);
  reduce_rows<<<kG, 256, 0, stream>>>(partials, lse);
  sub_lse<<<2048, 256, 0, stream>>>(out, lse);
}

// Round 14
// 909.745 us; speedup vs baseline: 1.1708x; 1.1708x over previous
//
#include <hip/hip_runtime.h>

#define DEV __device__ __forceinline__

typedef __attribute__((ext_vector_type(8))) short short8;
typedef __attribute__((ext_vector_type(4))) float f32x4;
typedef unsigned short u16;

constexpr int kV = 80000, kD = 300, kNN = 32, kEE = 64, kHH = 4, kCC = 75;
constexpr int kB = 32, kT = 35, kU = 1024, kVG = 50000;
constexpr int kG = kB * kT;          // 1120
constexpr int kM = kG;

constexpr size_t alignup(size_t x) { return (x + 255) & ~size_t(255); }
constexpr size_t OFF_BAR   = 0;       // 256 flag slots (1024 B)
constexpr size_t OFF_WSRC  = 1024;
constexpr size_t OFF_WDST  = alignup(OFF_WSRC + 1200 * 4);
constexpr size_t OFF_BIAS  = alignup(OFF_WDST + 1200 * 4);
constexpr size_t OFF_SIG   = alignup(OFF_BIAS + 3 * 4096 * 4);
constexpr size_t OFF_WX0   = alignup(OFF_SIG + (size_t)35 * 32 * 640 * 2);
constexpr size_t OFF_WX12  = alignup(OFF_WX0 + (size_t)4096 * 640 * 2);
constexpr size_t OFF_GATES = alignup(OFF_WX12 + (size_t)2 * 4096 * 1024 * 2);
constexpr size_t OFF_HIST  = alignup(OFF_GATES + (size_t)1120 * 4096 * 4);
constexpr size_t OFF_PART  = alignup(OFF_HIST + (size_t)3 * 35 * 32 * 1024 * 2);
constexpr size_t OFF_LSE   = alignup(OFF_PART + (size_t)1120 * 784 * 8);
constexpr size_t OFF_LINWB = alignup(OFF_LSE + 1120 * 4);
constexpr size_t kLinWBytes = (size_t)kVG * 1024 * 2;
constexpr size_t kNeedBW   = OFF_LINWB + kLinWBytes;

DEV u16 f2bf(float f) {
  union { float f; unsigned u; } v; v.f = f;
  unsigned r = v.u + 0x7fffu + ((v.u >> 16) & 1u);
  return (u16)(r >> 16);
}
DEV float fexp(float x) { return __builtin_amdgcn_exp2f(x * 1.4426950408889634f); }
DEV float fsigm(float x) {
  float t = __builtin_amdgcn_exp2f(-1.4426950408889634f * x);
  return __builtin_amdgcn_rcpf(1.f + t);
}
DEV float ftanh(float x) {
  float xc = fminf(fmaxf(x, -20.f), 20.f);
  float t = __builtin_amdgcn_exp2f(2.8853900817779268f * xc);
  return (t - 1.f) * __builtin_amdgcn_rcpf(t + 1.f);
}
DEV f32x4 mfma16(short8 a, short8 b, f32x4 c) {
  return __builtin_amdgcn_mfma_f32_16x16x32_bf16(a, b, c, 0, 0, 0);
}
// store a bf16 directly to the coherent LLC (bypass non-coherent per-XCD L2).
DEV void store_u16_llc(u16* p, u16 v) {
  unsigned vv = v;
  asm volatile("global_store_short %0, %1, off sc0 sc1"
               :: "v"(p), "v"(vv) : "memory");
}
// async global->LDS DMA, 16B/lane
DEV void gll16(const void* g, void* l) {
  __builtin_amdgcn_global_load_lds(
      (const __attribute__((address_space(1))) unsigned int*)g,
      (__attribute__((address_space(3))) unsigned int*)l, 16, 0, 0);
}
// load 8 fp32, convert to bf16 short8
DEV short8 ld8bf(const float* p) {
  float4 a = *(const float4*)p;
  float4 b = *(const float4*)(p + 4);
  u16 t[8] = {f2bf(a.x), f2bf(a.y), f2bf(a.z), f2bf(a.w),
              f2bf(b.x), f2bf(b.y), f2bf(b.z), f2bf(b.w)};
  return *(const short8*)t;
}

// ---------------- prep: ws_src/ws_dst (W @ att vectors), bias sums ----------
__global__ void prep_small(const float* __restrict__ gat_W,
                           const float* __restrict__ att_src,
                           const float* __restrict__ att_dst,
                           const float* __restrict__ b_ih,
                           const float* __restrict__ b_hh,
                           float* __restrict__ ws_src, float* __restrict__ ws_dst,
                           float* __restrict__ bias_sum) {
  int total = 1200 + 1200 + 3 * 4096;
  for (int i = blockIdx.x * blockDim.x + threadIdx.x; i < total; i += gridDim.x * blockDim.x) {
    if (i < 1200) {
      int d = i >> 2, h = i & 3;
      float s = 0.f;
      for (int c = 0; c < kCC; ++c) s += gat_W[d * 300 + h * kCC + c] * att_src[h * kCC + c];
      ws_src[i] = s;
    } else if (i < 2400) {
      int j = i - 1200; int d = j >> 2, h = j & 3;
      float s = 0.f;
      for (int c = 0; c < kCC; ++c) s += gat_W[d * 300 + h * kCC + c] * att_dst[h * kCC + c];
      ws_dst[j] = s;
    } else {
      int j = i - 2400;
      bias_sum[j] = b_ih[j] + b_hh[j];
    }
  }
}

// ---------------- prep: bf16 W_ih0 only -------------------------------------
__global__ void wx_prep(const float* __restrict__ W_ih0, u16* __restrict__ wx0) {
  const int n0 = 4096 * 640;
  for (int i = blockIdx.x * blockDim.x + threadIdx.x; i < n0; i += gridDim.x * blockDim.x) {
    int row = i / 640, col = i - row * 640;
    float v = (col < 600) ? W_ih0[row * 600 + col] : 0.f;
    wx0[i] = f2bf(v);
  }
}

// ---------------- prep: bf16 copy of lin_W ----------------------------------
__global__ void wb_conv(const float* __restrict__ W, u16* __restrict__ Wb) {
  const long n = (long)kVG * 1024;
  long stride = (long)gridDim.x * blockDim.x * 8;
  for (long i = (long)(blockIdx.x * blockDim.x + threadIdx.x) * 8; i < n; i += stride) {
    float4 a = *(const float4*)(W + i);
    float4 b = *(const float4*)(W + i + 4);
    u16 t[8] = {f2bf(a.x), f2bf(a.y), f2bf(a.z), f2bf(a.w),
                f2bf(b.x), f2bf(b.y), f2bf(b.z), f2bf(b.w)};
    *(uint4*)(Wb + i) = *(const uint4*)t;
  }
}

// ---------------- GAT (node-0 only, factored attention) ---------------------
__global__ void __launch_bounds__(256) gat_kernel(
    const int* __restrict__ x_indices, const int* __restrict__ edge_index,
    const float* __restrict__ X, const float* __restrict__ gat_W,
    const float* __restrict__ gat_bias, const float* __restrict__ ws_src,
    const float* __restrict__ ws_dst, u16* __restrict__ sig) {
  __shared__ float xs[32][301];
  __shared__ float a_s[32][4];
  __shared__ float a_d0[4];
  __shared__ float alpha[4][32];
  __shared__ float xw[4][301];
  __shared__ int allowed[32];
  int g = blockIdx.x, tid = threadIdx.x;
  const int* idx = x_indices + g * 32;
  for (int i = tid; i < 32 * 300; i += 256) {
    int j = i / 300, d2 = i - j * 300;
    xs[j][d2] = X[(size_t)idx[j] * 300 + d2];
  }
  if (tid < 32) allowed[tid] = (tid == 0) ? 1 : 0;
  __syncthreads();
  if (tid < 128) {
    int j = tid >> 2, h = tid & 3;
    float s = 0.f;
    for (int d2 = 0; d2 < 300; ++d2) s += xs[j][d2] * ws_src[d2 * 4 + h];
    a_s[j][h] = s;
  } else if (tid < 132) {
    int h = tid - 128; float s = 0.f;
    for (int d2 = 0; d2 < 300; ++d2) s += xs[0][d2] * ws_dst[d2 * 4 + h];
    a_d0[h] = s;
  } else if (tid >= 192) {
    int e = tid - 192;
    int src = edge_index[g * 128 + e];
    int dst = edge_index[g * 128 + 64 + e];
    if (dst == 0) allowed[src] = 1;
  }
  __syncthreads();
  if (tid < 4) {
    int h = tid;
    float ev[32];
    float mx = -1e30f;
    #pragma unroll
    for (int j = 0; j < 32; ++j) {
      float v = a_d0[h] + a_s[j][h];
      v = (v > 0.f) ? v : 0.2f * v;
      v = allowed[j] ? v : -1e9f;
      ev[j] = v; mx = fmaxf(mx, v);
    }
    float ssum = 0.f;
    #pragma unroll
    for (int j = 0; j < 32; ++j) { float p = fexp(ev[j] - mx); ev[j] = p; ssum += p; }
    float inv = 1.f / ssum;
    #pragma unroll
    for (int j = 0; j < 32; ++j) alpha[h][j] = ev[j] * inv;
  }
  __syncthreads();
  for (int i = tid; i < 4 * 300; i += 256) {
    int h = i / 300, d2 = i - h * 300;
    float s = 0.f;
    #pragma unroll
    for (int j = 0; j < 32; ++j) s += alpha[h][j] * xs[j][d2];
    xw[h][d2] = s;
  }
  __syncthreads();
  int t = g % 35, b = g / 35;
  u16* srow = sig + ((size_t)t * 32 + b) * 640;
  for (int hc = tid; hc < 300; hc += 256) {
    srow[hc] = f2bf(xs[0][hc]);           // curr_emb = X[idx 0]
    int h = hc / 75;
    float s = gat_bias[hc];
    for (int d2 = 0; d2 < 300; ++d2) s += xw[h][d2] * gat_W[d2 * 300 + hc];
    srow[300 + hc] = f2bf(s);
  }
  for (int i2 = 600 + tid; i2 < 640; i2 += 256) srow[i2] = 0;  // zero pad
}

// ---------------- bulk input-gate GEMM (gll16 dbuf + swizzled LDS) ----------
// gates written INTERLEAVED: gates[m][u*4+g]  (one float4 per (m,unit))
__global__ void __launch_bounds__(256, 4) gemm_ig(
    const u16* __restrict__ A, const u16* __restrict__ Bw,
    float* __restrict__ gates, int K) {
  int bid = blockIdx.x;
  int bm = bid % 9, bn = bid / 9;
  int m0 = bm * 128, n0 = bn * 128;
  int tid = threadIdx.x, w = tid >> 6, lane = tid & 63, l15 = lane & 15, lhi = lane >> 4;
  int wm = w & 1, wn = w >> 1;
  __shared__ u16 As[2][128][32];
  __shared__ u16 Bs[2][128][32];
  int cl = ((lane & 3) ^ ((lane >> 3) & 3)) * 8;
  int am0 = m0 + w * 32 + (lane >> 2);
  int am1 = am0 + 16;
  const u16* arow0 = A + (size_t)((am0 < kM) ? am0 : 0) * K + cl;
  const u16* arow1 = A + (size_t)((am1 < kM) ? am1 : 0) * K + cl;
  int bn0r = n0 + w * 32 + (lane >> 2);
  const u16* brow0 = Bw + (size_t)bn0r * K + cl;
  const u16* brow1 = Bw + (size_t)(bn0r + 16) * K + cl;
  const int koff = (lhi ^ ((l15 >> 1) & 3)) * 8;  // read-side swizzle

  f32x4 acc[4][4];
  #pragma unroll
  for (int i = 0; i < 4; ++i)
    #pragma unroll
    for (int j = 0; j < 4; ++j) { f32x4 z = {0.f, 0.f, 0.f, 0.f}; acc[i][j] = z; }

  auto ISSUE = [&](int k0, int buf) {
    gll16(arow0 + k0, &As[buf][w * 32][0]);
    gll16(arow1 + k0, &As[buf][w * 32 + 16][0]);
    gll16(brow0 + k0, &Bs[buf][w * 32][0]);
    gll16(brow1 + k0, &Bs[buf][w * 32 + 16][0]);
  };
  int nkt = K >> 5;
  ISSUE(0, 0);
  for (int kt = 0; kt < nkt; ++kt) {
    int cur = kt & 1;
    if (kt < nkt - 1) {
      ISSUE((kt + 1) * 32, cur ^ 1);
      asm volatile("s_waitcnt vmcnt(4)" ::: "memory");
    } else {
      asm volatile("s_waitcnt vmcnt(0)" ::: "memory");
    }
    __builtin_amdgcn_s_barrier();
    __builtin_amdgcn_sched_barrier(0);
    short8 bfr[4];
    #pragma unroll
    for (int nt = 0; nt < 4; ++nt)
      bfr[nt] = *(const short8*)&Bs[cur][wn * 64 + nt * 16 + l15][koff];
    #pragma unroll
    for (int mt = 0; mt < 4; ++mt) {
      short8 af = *(const short8*)&As[cur][wm * 64 + mt * 16 + l15][koff];
      #pragma unroll
      for (int nt = 0; nt < 4; ++nt)
        acc[mt][nt] = mfma16(af, bfr[nt], acc[mt][nt]);
    }
    __builtin_amdgcn_sched_barrier(0);
    __builtin_amdgcn_s_barrier();
  }
  #pragma unroll
  for (int mt = 0; mt < 4; ++mt) {
    #pragma unroll
    for (int r = 0; r < 4; ++r) {
      int m = m0 + wm * 64 + mt * 16 + lhi * 4 + r;
      if (m < kM) {
        float* orow = gates + (size_t)m * 4096;
        #pragma unroll
        for (int nt = 0; nt < 4; ++nt) {
          int n = n0 + wn * 64 + nt * 16 + l15;
          orow[(n & 1023) * 4 + (n >> 10)] = acc[mt][nt][r];
        }
      }
    }
  }
}

// ---------------- fused 3-layer LSTM wavefront, weights in VGPRs ------------
// 256 blocks, block p owns units [4p,4p+4) for ALL layers. 37 supersteps:
// layer0 t=s, layer1 t=s-1, layer2 t=s-2. Each wave holds its K-slice of all
// 5 weight matrices (16 rows each) in registers (5 x 8 short8 = 160 VGPR).
// h0 shared by layer0-h & layer1-x; h1 shared by layer1-h & layer2-x.
__global__ void __launch_bounds__(256, 1) lstm_fused012(
    const float* __restrict__ W_hh,      // [3][4096][1024]
    const float* __restrict__ W_ih_rest, // [2][4096][1024]
    const float* __restrict__ gates,     // [1120][1024][4] f32 (layer0 x-part)
    const float* __restrict__ bias_sum,  // [3][4096]
    u16* __restrict__ hist0, u16* __restrict__ hist1, u16* __restrict__ hist2,
    unsigned* __restrict__ flags) {
  const int p = blockIdx.x;            // 0..255
  const int u0 = p * 4;
  const int tid = threadIdx.x;
  const int w = tid >> 6, lane = tid & 63, l15 = lane & 15, lhi = lane >> 4;
  __shared__ float pred0[4][16][33];
  __shared__ float pred1[4][16][33];
  __shared__ float pred2[4][16][33];

  // prologue: weight fragments -> registers (fp32 -> bf16 inline)
  const int kbase = w * 256;
  const int grow = (l15 >> 2) * 1024 + u0 + (l15 & 3);  // global weight row
  size_t rowoff = (size_t)grow * 1024 + kbase + lhi * 8;
  const float* pw0 = W_hh + rowoff;
  const float* pw1 = W_hh + (size_t)4096 * 1024 + rowoff;
  const float* pw2 = W_hh + (size_t)2 * 4096 * 1024 + rowoff;
  const float* pi1 = W_ih_rest + rowoff;
  const float* pi2 = W_ih_rest + (size_t)4096 * 1024 + rowoff;
  short8 rw0[8], rw1[8], rw2[8], ri1[8], ri2[8];
  #pragma unroll
  for (int kk = 0; kk < 8; ++kk) {
    rw0[kk] = ld8bf(pw0 + kk * 32);
    rw1[kk] = ld8bf(pw1 + kk * 32);
    rw2[kk] = ld8bf(pw2 + kk * 32);
    ri1[kk] = ld8bf(pi1 + kk * 32);
    ri2[kk] = ld8bf(pi2 + kk * 32);
  }

  // pointwise task assignment:
  //  task A: all 256 threads -> layer (tid>>7), batch (tid&127)>>2, unit tid&3
  //  task B: threads <128 -> layer 2, batch tid>>2, unit tid&3
  const int layerA = tid >> 7;
  const int pbA = (tid & 127) >> 2, pjA = tid & 3;
  float biasA[4], biasB[4];
  #pragma unroll
  for (int g = 0; g < 4; ++g) {
    biasA[g] = bias_sum[layerA * 4096 + g * 1024 + u0 + pjA];
    biasB[g] = bias_sum[2 * 4096 + g * 1024 + u0 + pjA];
  }
  float cA = 0.f, cB = 0.f;
  const unsigned* myflag = flags + w * 64 + lane;  // wave's 64 producers
  __syncthreads();

  for (int s = 0; s < 37; ++s) {
    if (s >= 1) {
      unsigned tgt = (unsigned)s;
      while (!__all((int)(__hip_atomic_load(myflag, __ATOMIC_RELAXED,
                                            __HIP_MEMORY_SCOPE_AGENT) >= tgt)))
        __builtin_amdgcn_s_sleep(1);
      asm volatile("" ::: "memory");   // pin h loads behind the wait
    }
    f32x4 a00 = {0,0,0,0}, a01 = {0,0,0,0};
    f32x4 a10 = {0,0,0,0}, a11 = {0,0,0,0};
    f32x4 a20 = {0,0,0,0}, a21 = {0,0,0,0};
    const bool useH0 = (s >= 1 && s <= 35);
    const bool l0h   = (s >= 1 && s < 35);
    const bool useH1 = (s >= 2 && s <= 36);
    const bool l1h   = (s >= 2 && s <= 35);
    const bool useH2 = (s >= 3 && s <= 36);
    if (useH0) {                       // h0[s-1]: layer0-h + layer1-x
      const u16* hp = hist0 + (size_t)(s - 1) * 32 * 1024;
      const u16* b0p = hp + l15 * 1024 + lhi * 8 + kbase;
      const u16* b1p = hp + (l15 + 16) * 1024 + lhi * 8 + kbase;
      #pragma unroll
      for (int kk = 0; kk < 8; ++kk) {
        short8 b0 = *(const short8*)(b0p + kk * 32);
        short8 b1 = *(const short8*)(b1p + kk * 32);
        if (l0h) { a00 = mfma16(rw0[kk], b0, a00); a01 = mfma16(rw0[kk], b1, a01); }
        a10 = mfma16(ri1[kk], b0, a10);
        a11 = mfma16(ri1[kk], b1, a11);
      }
    }
    if (useH1) {                       // h1[s-2]: layer1-h + layer2-x
      const u16* hp = hist1 + (size_t)(s - 2) * 32 * 1024;
      const u16* c0p = hp + l15 * 1024 + lhi * 8 + kbase;
      const u16* c1p = hp + (l15 + 16) * 1024 + lhi * 8 + kbase;
      #pragma unroll
      for (int kk = 0; kk < 8; ++kk) {
        short8 c0 = *(const short8*)(c0p + kk * 32);
        short8 c1 = *(const short8*)(c1p + kk * 32);
        if (l1h) { a10 = mfma16(rw1[kk], c0, a10); a11 = mfma16(rw1[kk], c1, a11); }
        a20 = mfma16(ri2[kk], c0, a20);
        a21 = mfma16(ri2[kk], c1, a21);
      }
    }
    if (useH2) {                       // h2[s-3]: layer2-h
      const u16* hp = hist2 + (size_t)(s - 3) * 32 * 1024;
      const u16* d0p = hp + l15 * 1024 + lhi * 8 + kbase;
      const u16* d1p = hp + (l15 + 16) * 1024 + lhi * 8 + kbase;
      #pragma unroll
      for (int kk = 0; kk < 8; ++kk) {
        short8 d0 = *(const short8*)(d0p + kk * 32);
        short8 d1 = *(const short8*)(d1p + kk * 32);
        a20 = mfma16(rw2[kk], d0, a20);
        a21 = mfma16(rw2[kk], d1, a21);
      }
    }
    #pragma unroll
    for (int r = 0; r < 4; ++r) {
      pred0[w][lhi * 4 + r][l15]      = a00[r];
      pred0[w][lhi * 4 + r][l15 + 16] = a01[r];
      pred1[w][lhi * 4 + r][l15]      = a10[r];
      pred1[w][lhi * 4 + r][l15 + 16] = a11[r];
      pred2[w][lhi * 4 + r][l15]      = a20[r];
      pred2[w][lhi * 4 + r][l15 + 16] = a21[r];
    }
    __syncthreads();
    // task A: layer0 (t=s) or layer1 (t=s-1)
    const bool actA = (layerA == 0) ? (s < 35) : (s >= 1 && s <= 35);
    if (actA) {
      int row = 0;
      float pre[4];
      if (layerA == 0) {
        #pragma unroll
        for (int g = 0; g < 4; ++g) {
          row = g * 4 + pjA;
          pre[g] = pred0[0][row][pbA] + pred0[1][row][pbA] +
                   pred0[2][row][pbA] + pred0[3][row][pbA];
        }
        float4 gx = ((const float4*)gates)[(size_t)(s * 32 + pbA) * 1024 + u0 + pjA];
        pre[0] += gx.x; pre[1] += gx.y; pre[2] += gx.z; pre[3] += gx.w;
      } else {
        #pragma unroll
        for (int g = 0; g < 4; ++g) {
          row = g * 4 + pjA;
          pre[g] = pred1[0][row][pbA] + pred1[1][row][pbA] +
                   pred1[2][row][pbA] + pred1[3][row][pbA];
        }
      }
      float iv = pre[0] + biasA[0];
      float fv = pre[1] + biasA[1];
      float gv = pre[2] + biasA[2];
      float ov = pre[3] + biasA[3];
      float cc = fsigm(fv) * cA + fsigm(iv) * ftanh(gv);
      float hh = fsigm(ov) * ftanh(cc);
      cA = cc;
      int t = (layerA == 0) ? s : (s - 1);
      u16* dst = (layerA == 0) ? hist0 : hist1;
      store_u16_llc(dst + ((size_t)(t * 32 + pbA) << 10) + u0 + pjA, f2bf(hh));
    }
    // task B: layer2 (t=s-2), threads < 128
    if (tid < 128 && s >= 2) {
      float pre[4];
      #pragma unroll
      for (int g = 0; g < 4; ++g) {
        int row = g * 4 + pjA;
        pre[g] = pred2[0][row][pbA] + pred2[1][row][pbA] +
                 pred2[2][row][pbA] + pred2[3][row][pbA];
      }
      float iv = pre[0] + biasB[0];
      float fv = pre[1] + biasB[1];
      float gv = pre[2] + biasB[2];
      float ov = pre[3] + biasB[3];
      float cc = fsigm(fv) * cB + fsigm(iv) * ftanh(gv);
      float hh = fsigm(ov) * ftanh(cc);
      cB = cc;
      int t = s - 2;
      store_u16_llc(hist2 + ((size_t)(t * 32 + pbA) << 10) + u0 + pjA, f2bf(hh));
    }
    __syncthreads();   // drains LLC stores (vmcnt 0) + pred reuse safety
    if (s < 36 && tid == 0)
      __hip_atomic_store(flags + p, (unsigned)(s + 1),
                         __ATOMIC_RELAXED, __HIP_MEMORY_SCOPE_AGENT);
  }
}

// ---------------- logits GEMM epilogue --------------------------------------
DEV void logits_epilogue(f32x4 (&acc)[4][4], int m0, int n0, int wm, int wn,
                         int l15, int lhi, const float* lin_b,
                         float* out, float2* partials, int bn) {
  float bcol[4]; int ncol[4];
  #pragma unroll
  for (int nt = 0; nt < 4; ++nt) {
    int n = n0 + wn * 64 + nt * 16 + l15;
    ncol[nt] = n;
    bcol[nt] = (n < kVG) ? lin_b[n] : -INFINITY;
  }
  #pragma unroll
  for (int mt = 0; mt < 4; ++mt) {
    #pragma unroll
    for (int r = 0; r < 4; ++r) {
      int m = m0 + wm * 64 + mt * 16 + lhi * 4 + r;
      float v0 = acc[mt][0][r] + bcol[0];
      float v1 = acc[mt][1][r] + bcol[1];
      float v2 = acc[mt][2][r] + bcol[2];
      float v3 = acc[mt][3][r] + bcol[3];
      bool mok = (m < kM);
      if (mok) {
        float* orow = out + (size_t)m * kVG;
        if (ncol[0] < kVG) orow[ncol[0]] = v0;
        if (ncol[1] < kVG) orow[ncol[1]] = v1;
        if (ncol[2] < kVG) orow[ncol[2]] = v2;
        if (ncol[3] < kVG) orow[ncol[3]] = v3;
      }
      float mx = fmaxf(fmaxf(v0, v1), fmaxf(v2, v3));
      #pragma unroll
      for (int d2 = 1; d2 < 16; d2 <<= 1) mx = fmaxf(mx, __shfl_xor(mx, d2, 64));
      float sv = 0.f;
      sv += (v0 > -1e30f) ? fexp(v0 - mx) : 0.f;
      sv += (v1 > -1e30f) ? fexp(v1 - mx) : 0.f;
      sv += (v2 > -1e30f) ? fexp(v2 - mx) : 0.f;
      sv += (v3 > -1e30f) ? fexp(v3 - mx) : 0.f;
      #pragma unroll
      for (int d2 = 1; d2 < 16; d2 <<= 1) sv += __shfl_xor(sv, d2, 64);
      if (mok && l15 == 0)
        partials[(size_t)m * 784 + bn * 2 + wn] = make_float2(mx, sv);
    }
  }
}

// ---------------- logits GEMM (gll16 dbuf + swizzled LDS) -------------------
__global__ void __launch_bounds__(256, 4) gemm_logits_async(
    const u16* __restrict__ hist2, const u16* __restrict__ linwb,
    const float* __restrict__ lin_b, float* __restrict__ out,
    float2* __restrict__ partials) {
  int nwg = gridDim.x, orig = blockIdx.x;
  int q = nwg >> 3, r = nwg & 7, xcd = orig & 7, off = orig >> 3;
  int bid = (xcd < r ? xcd * (q + 1) : r * (q + 1) + (xcd - r) * q) + off;
  int bm = bid % 9, bn = bid / 9;
  int m0 = bm * 128, n0 = bn * 128;
  int tid = threadIdx.x, w = tid >> 6, lane = tid & 63, l15 = lane & 15, lhi = lane >> 4;
  int wm = w & 1, wn = w >> 1;
  __shared__ u16 As[2][128][32];
  __shared__ u16 Bs[2][128][32];
  int cl = ((lane & 3) ^ ((lane >> 3) & 3)) * 8;
  int am0 = m0 + w * 32 + (lane >> 2);
  int am1 = am0 + 16;
  int mm0 = (am0 < kM) ? am0 : 0, mm1 = (am1 < kM) ? am1 : 0;
  const u16* arow0 = hist2 + (((size_t)((mm0 % 35) * 32 + mm0 / 35)) << 10) + cl;
  const u16* arow1 = hist2 + (((size_t)((mm1 % 35) * 32 + mm1 / 35)) << 10) + cl;
  int nr0 = n0 + w * 32 + (lane >> 2);
  int nn0 = (nr0 < kVG) ? nr0 : 0, nn1 = (nr0 + 16 < kVG) ? nr0 + 16 : 0;
  const u16* brow0 = linwb + ((size_t)nn0 << 10) + cl;
  const u16* brow1 = linwb + ((size_t)nn1 << 10) + cl;
  const int koff = (lhi ^ ((l15 >> 1) & 3)) * 8;

  f32x4 acc[4][4];
  #pragma unroll
  for (int i = 0; i < 4; ++i)
    #pragma unroll
    for (int j = 0; j < 4; ++j) { f32x4 z = {0.f, 0.f, 0.f, 0.f}; acc[i][j] = z; }

  auto ISSUE = [&](int k0, int buf) {
    gll16(arow0 + k0, &As[buf][w * 32][0]);
    gll16(arow1 + k0, &As[buf][w * 32 + 16][0]);
    gll16(brow0 + k0, &Bs[buf][w * 32][0]);
    gll16(brow1 + k0, &Bs[buf][w * 32 + 16][0]);
  };
  ISSUE(0, 0);
  for (int kt = 0; kt < 32; ++kt) {
    int cur = kt & 1;
    if (kt < 31) {
      ISSUE((kt + 1) * 32, cur ^ 1);
      asm volatile("s_waitcnt vmcnt(4)" ::: "memory");
    } else {
      asm volatile("s_waitcnt vmcnt(0)" ::: "memory");
    }
    __builtin_amdgcn_s_barrier();
    __builtin_amdgcn_sched_barrier(0);
    short8 bfr[4];
    #pragma unroll
    for (int nt = 0; nt < 4; ++nt)
      bfr[nt] = *(const short8*)&Bs[cur][wn * 64 + nt * 16 + l15][koff];
    #pragma unroll
    for (int mt = 0; mt < 4; ++mt) {
      short8 af = *(const short8*)&As[cur][wm * 64 + mt * 16 + l15][koff];
      #pragma unroll
      for (int nt = 0; nt < 4; ++nt)
        acc[mt][nt] = mfma16(af, bfr[nt], acc[mt][nt]);
    }
    __builtin_amdgcn_sched_barrier(0);
    __builtin_amdgcn_s_barrier();
  }
  logits_epilogue(acc, m0, n0, wm, wn, l15, lhi, lin_b, out, partials, bn);
}

// fallback (no bf16 workspace image): reg-staged, fp32 B inline-converted
__global__ void __launch_bounds__(256, 1) gemm_logits_fb(
    const u16* __restrict__ hist2, const float* __restrict__ lin_W,
    const float* __restrict__ lin_b, float* __restrict__ out,
    float2* __restrict__ partials) {
  int nwg = gridDim.x, orig = blockIdx.x;
  int q = nwg >> 3, r = nwg & 7, xcd = orig & 7, off = orig >> 3;
  int bid = (xcd < r ? xcd * (q + 1) : r * (q + 1) + (xcd - r) * q) + off;
  int bm = bid % 9, bn = bid / 9;
  int m0 = bm * 128, n0 = bn * 128;
  int tid = threadIdx.x, w = tid >> 6, lane = tid & 63, l15 = lane & 15, lhi = lane >> 4;
  int wm = w & 1, wn = w >> 1;
  __shared__ u16 As[128][40];
  __shared__ u16 Bs[128][40];
  f32x4 acc[4][4];
  #pragma unroll
  for (int i = 0; i < 4; ++i)
    #pragma unroll
    for (int j = 0; j < 4; ++j) { f32x4 z = {0.f, 0.f, 0.f, 0.f}; acc[i][j] = z; }
  for (int kt = 0; kt < 32; ++kt) {
    int k0 = kt * 32;
    #pragma unroll
    for (int q2 = 0; q2 < 2; ++q2) {
      int c = tid * 2 + q2; int row = c >> 2; int ch = c & 3;
      int m = m0 + row;
      uint4 av{0u, 0u, 0u, 0u};
      if (m < kM) {
        int b = m / 35; int t = m - b * 35;
        av = *(const uint4*)(hist2 + ((size_t)(t * 32 + b) << 10) + k0 + ch * 8);
      }
      *(uint4*)&As[row][ch * 8] = av;
      int n = n0 + row;
      uint4 bv{0u, 0u, 0u, 0u};
      if (n < kVG) {
        const float* src = lin_W + (size_t)n * 1024 + k0 + ch * 8;
        float4 f0 = *(const float4*)(src);
        float4 f1 = *(const float4*)(src + 4);
        bv.x = (unsigned)f2bf(f0.x) | ((unsigned)f2bf(f0.y) << 16);
        bv.y = (unsigned)f2bf(f0.z) | ((unsigned)f2bf(f0.w) << 16);
        bv.z = (unsigned)f2bf(f1.x) | ((unsigned)f2bf(f1.y) << 16);
        bv.w = (unsigned)f2bf(f1.z) | ((unsigned)f2bf(f1.w) << 16);
      }
      *(uint4*)&Bs[row][ch * 8] = bv;
    }
    __syncthreads();
    short8 bfr[4];
    #pragma unroll
    for (int nt = 0; nt < 4; ++nt)
      bfr[nt] = *(const short8*)&Bs[wn * 64 + nt * 16 + l15][lhi * 8];
    #pragma unroll
    for (int mt = 0; mt < 4; ++mt) {
      short8 af = *(const short8*)&As[wm * 64 + mt * 16 + l15][lhi * 8];
      #pragma unroll
      for (int nt = 0; nt < 4; ++nt)
        acc[mt][nt] = mfma16(af, bfr[nt], acc[mt][nt]);
    }
    __syncthreads();
  }
  logits_epilogue(acc, m0, n0, wm, wn, l15, lhi, lin_b, out, partials, bn);
}

// ---------------- row logsumexp reduce --------------------------------------
__global__ void reduce_rows(const float2* __restrict__ partials, float* __restrict__ lse) {
  int m = blockIdx.x, tid = threadIdx.x;
  float mx = -INFINITY, s = 0.f;
  for (int j = tid; j < 782; j += 256) {
    float2 p = partials[(size_t)m * 784 + j];
    if (p.x > mx) { s = s * fexp(mx - p.x) + p.y; mx = p.x; }
    else          { s += p.y * fexp(p.x - mx); }
  }
  for (int d = 1; d < 64; d <<= 1) {
    float omx = __shfl_xor(mx, d, 64);
    float os  = __shfl_xor(s, d, 64);
    if (omx > mx) { s = s * fexp(mx - omx) + os; mx = omx; }
    else          { s += os * fexp(omx - mx); }
  }
  __shared__ float smx[4], ssum[4];
  int w = tid >> 6;
  if ((tid & 63) == 0) { smx[w] = mx; ssum[w] = s; }
  __syncthreads();
  if (tid == 0) {
    for (int i = 1; i < 4; ++i) {
      float omx = smx[i], os = ssum[i];
      if (omx > mx) { s = s * fexp(mx - omx) + os; mx = omx; }
      else          { s += os * fexp(omx - mx); }
    }
    lse[m] = mx + logf(s);
  }
}

// ---------------- in-place log_softmax subtract -----------------------------
__global__ void sub_lse(float* __restrict__ out, const float* __restrict__ lse) {
  const int total4 = 14000000;  // 1120*50000/4
  for (int i = blockIdx.x * blockDim.x + threadIdx.x; i < total4; i += gridDim.x * blockDim.x) {
    int m = i / 12500;
    float4 v = ((float4*)out)[i];
    float L = lse[m];
    v.x -= L; v.y -= L; v.z -= L; v.w -= L;
    ((float4*)out)[i] = v;
  }
}

// ---------------- launch ----------------------------------------------------
extern "C" void kernel_launch(void* const* d_in, const int* in_sizes, int n_in,
                              void* d_out, int out_size, void* d_ws, size_t ws_size,
                              hipStream_t stream) {
  const int*   x_indices  = (const int*)d_in[0];
  const int*   edge_index = (const int*)d_in[1];
  const float* X          = (const float*)d_in[2];
  const float* gat_W      = (const float*)d_in[3];
  const float* att_src    = (const float*)d_in[4];
  const float* att_dst    = (const float*)d_in[5];
  const float* gat_bias   = (const float*)d_in[6];
  const float* W_ih0      = (const float*)d_in[7];
  const float* W_ih_rest  = (const float*)d_in[8];
  const float* W_hh       = (const float*)d_in[9];
  const float* b_ih       = (const float*)d_in[10];
  const float* b_hh       = (const float*)d_in[11];
  const float* lin_W      = (const float*)d_in[12];
  const float* lin_b      = (const float*)d_in[13];
  float* out = (float*)d_out;
  char* ws = (char*)d_ws;

  unsigned* flags    = (unsigned*)(ws + OFF_BAR);
  float*    ws_src   = (float*)(ws + OFF_WSRC);
  float*    ws_dst   = (float*)(ws + OFF_WDST);
  float*    bias_sum = (float*)(ws + OFF_BIAS);
  u16*      sig      = (u16*)(ws + OFF_SIG);
  u16*      wx0      = (u16*)(ws + OFF_WX0);
  float*    gates    = (float*)(ws + OFF_GATES);
  u16*      hist     = (u16*)(ws + OFF_HIST);
  float2*   partials = (float2*)(ws + OFF_PART);
  float*    lse      = (float*)(ws + OFF_LSE);
  u16*      linwb    = (u16*)(ws + OFF_LINWB);
  bool use_bw = (ws_size >= kNeedBW);

  u16* hist0 = hist;
  u16* hist1 = hist + (size_t)35 * 32 * 1024;
  u16* hist2 = hist + (size_t)2 * 35 * 32 * 1024;

  hipMemsetAsync(ws + OFF_BAR, 0, 1024, stream);
  prep_small<<<64, 256, 0, stream>>>(gat_W, att_src, att_dst, b_ih, b_hh,
                                     ws_src, ws_dst, bias_sum);
  wx_prep<<<512, 256, 0, stream>>>(W_ih0, wx0);
  if (use_bw) wb_conv<<<2048, 256, 0, stream>>>(lin_W, linwb);
  gat_kernel<<<kG, 256, 0, stream>>>(x_indices, edge_index, X, gat_W, gat_bias,
                                     ws_src, ws_dst, sig);
  // layer 0 input transform (bulk)
  gemm_ig<<<288, 256, 0, stream>>>(sig, wx0, gates, 640);
  // fused 3-layer wavefront (37 supersteps, weights in VGPRs, dataflow flags)
  lstm_fused012<<<256, 256, 0, stream>>>(W_hh, W_ih_rest, gates, bias_sum,
                                         hist0, hist1, hist2, flags);
  // logits + log_softmax
  if (use_bw)
    gemm_logits_async<<<9 * 391, 256, 0, stream>>>(hist2, linwb, lin_b, out, partials);
  else
    gemm_logits_fb<<<9 * 391, 256, 0, stream>>>(hist2, lin_W, lin_b, out, partials);
  reduce_rows<<<kG, 256, 0, stream>>>(partials, lse);
  sub_lse<<<2048, 256, 0, stream>>>(out, lse);
}

// Round 15
// 889.925 us; speedup vs baseline: 1.1968x; 1.0223x over previous
//
#include <hip/hip_runtime.h>

#define DEV __device__ __forceinline__

typedef __attribute__((ext_vector_type(8))) short short8;
typedef __attribute__((ext_vector_type(4))) float f32x4;
typedef unsigned short u16;

constexpr int kV = 80000, kD = 300, kNN = 32, kEE = 64, kHH = 4, kCC = 75;
constexpr int kB = 32, kT = 35, kU = 1024, kVG = 50000;
constexpr int kG = kB * kT;          // 1120
constexpr int kM = kG;

constexpr size_t alignup(size_t x) { return (x + 255) & ~size_t(255); }
constexpr size_t OFF_BAR   = 0;       // 256 flag slots (1024 B)
constexpr size_t OFF_WSRC  = 1024;
constexpr size_t OFF_WDST  = alignup(OFF_WSRC + 1200 * 4);
constexpr size_t OFF_BIAS  = alignup(OFF_WDST + 1200 * 4);
constexpr size_t OFF_SIG   = alignup(OFF_BIAS + 3 * 4096 * 4);
constexpr size_t OFF_WX0   = alignup(OFF_SIG + (size_t)35 * 32 * 640 * 2);
constexpr size_t OFF_WX12  = alignup(OFF_WX0 + (size_t)4096 * 640 * 2);
constexpr size_t OFF_GATES = alignup(OFF_WX12 + (size_t)2 * 4096 * 1024 * 2);
constexpr size_t OFF_HIST  = alignup(OFF_GATES + (size_t)1120 * 4096 * 4);
constexpr size_t OFF_PART  = alignup(OFF_HIST + (size_t)3 * 35 * 32 * 1024 * 2);
constexpr size_t OFF_LSE   = alignup(OFF_PART + (size_t)1120 * 784 * 8);
constexpr size_t OFF_LINWB = alignup(OFF_LSE + 1120 * 4);
constexpr size_t kLinWBytes = (size_t)kVG * 1024 * 2;
constexpr size_t kNeedBW   = OFF_LINWB + kLinWBytes;

DEV u16 f2bf(float f) {
  union { float f; unsigned u; } v; v.f = f;
  unsigned r = v.u + 0x7fffu + ((v.u >> 16) & 1u);
  return (u16)(r >> 16);
}
DEV float fexp(float x) { return __builtin_amdgcn_exp2f(x * 1.4426950408889634f); }
DEV float fsigm(float x) {
  float t = __builtin_amdgcn_exp2f(-1.4426950408889634f * x);
  return __builtin_amdgcn_rcpf(1.f + t);
}
DEV float ftanh(float x) {
  float xc = fminf(fmaxf(x, -20.f), 20.f);
  float t = __builtin_amdgcn_exp2f(2.8853900817779268f * xc);
  return (t - 1.f) * __builtin_amdgcn_rcpf(t + 1.f);
}
DEV f32x4 mfma16(short8 a, short8 b, f32x4 c) {
  return __builtin_amdgcn_mfma_f32_16x16x32_bf16(a, b, c, 0, 0, 0);
}
// store a bf16 directly to the coherent LLC (bypass non-coherent per-XCD L2).
DEV void store_u16_llc(u16* p, u16 v) {
  unsigned vv = v;
  asm volatile("global_store_short %0, %1, off sc0 sc1"
               :: "v"(p), "v"(vv) : "memory");
}
// async global->LDS DMA, 16B/lane
DEV void gll16(const void* g, void* l) {
  __builtin_amdgcn_global_load_lds(
      (const __attribute__((address_space(1))) unsigned int*)g,
      (__attribute__((address_space(3))) unsigned int*)l, 16, 0, 0);
}
// load 8 fp32, convert to bf16 short8
DEV short8 ld8bf(const float* p) {
  float4 a = *(const float4*)p;
  float4 b = *(const float4*)(p + 4);
  u16 t[8] = {f2bf(a.x), f2bf(a.y), f2bf(a.z), f2bf(a.w),
              f2bf(b.x), f2bf(b.y), f2bf(b.z), f2bf(b.w)};
  return *(const short8*)t;
}

// ---------------- prep: ws_src/ws_dst (W @ att vectors), bias sums ----------
__global__ void prep_small(const float* __restrict__ gat_W,
                           const float* __restrict__ att_src,
                           const float* __restrict__ att_dst,
                           const float* __restrict__ b_ih,
                           const float* __restrict__ b_hh,
                           float* __restrict__ ws_src, float* __restrict__ ws_dst,
                           float* __restrict__ bias_sum) {
  int total = 1200 + 1200 + 3 * 4096;
  for (int i = blockIdx.x * blockDim.x + threadIdx.x; i < total; i += gridDim.x * blockDim.x) {
    if (i < 1200) {
      int d = i >> 2, h = i & 3;
      float s = 0.f;
      for (int c = 0; c < kCC; ++c) s += gat_W[d * 300 + h * kCC + c] * att_src[h * kCC + c];
      ws_src[i] = s;
    } else if (i < 2400) {
      int j = i - 1200; int d = j >> 2, h = j & 3;
      float s = 0.f;
      for (int c = 0; c < kCC; ++c) s += gat_W[d * 300 + h * kCC + c] * att_dst[h * kCC + c];
      ws_dst[j] = s;
    } else {
      int j = i - 2400;
      bias_sum[j] = b_ih[j] + b_hh[j];
    }
  }
}

// ---------------- prep: bf16 W_ih0 only -------------------------------------
__global__ void wx_prep(const float* __restrict__ W_ih0, u16* __restrict__ wx0) {
  const int n0 = 4096 * 640;
  for (int i = blockIdx.x * blockDim.x + threadIdx.x; i < n0; i += gridDim.x * blockDim.x) {
    int row = i / 640, col = i - row * 640;
    float v = (col < 600) ? W_ih0[row * 600 + col] : 0.f;
    wx0[i] = f2bf(v);
  }
}

// ---------------- prep: bf16 copy of lin_W ----------------------------------
__global__ void wb_conv(const float* __restrict__ W, u16* __restrict__ Wb) {
  const long n = (long)kVG * 1024;
  long stride = (long)gridDim.x * blockDim.x * 8;
  for (long i = (long)(blockIdx.x * blockDim.x + threadIdx.x) * 8; i < n; i += stride) {
    float4 a = *(const float4*)(W + i);
    float4 b = *(const float4*)(W + i + 4);
    u16 t[8] = {f2bf(a.x), f2bf(a.y), f2bf(a.z), f2bf(a.w),
                f2bf(b.x), f2bf(b.y), f2bf(b.z), f2bf(b.w)};
    *(uint4*)(Wb + i) = *(const uint4*)t;
  }
}

// ---------------- GAT (node-0 only, factored attention) ---------------------
__global__ void __launch_bounds__(256) gat_kernel(
    const int* __restrict__ x_indices, const int* __restrict__ edge_index,
    const float* __restrict__ X, const float* __restrict__ gat_W,
    const float* __restrict__ gat_bias, const float* __restrict__ ws_src,
    const float* __restrict__ ws_dst, u16* __restrict__ sig) {
  __shared__ float xs[32][301];
  __shared__ float a_s[32][4];
  __shared__ float a_d0[4];
  __shared__ float alpha[4][32];
  __shared__ float xw[4][301];
  __shared__ int allowed[32];
  int g = blockIdx.x, tid = threadIdx.x;
  const int* idx = x_indices + g * 32;
  for (int i = tid; i < 32 * 300; i += 256) {
    int j = i / 300, d2 = i - j * 300;
    xs[j][d2] = X[(size_t)idx[j] * 300 + d2];
  }
  if (tid < 32) allowed[tid] = (tid == 0) ? 1 : 0;
  __syncthreads();
  if (tid < 128) {
    int j = tid >> 2, h = tid & 3;
    float s = 0.f;
    for (int d2 = 0; d2 < 300; ++d2) s += xs[j][d2] * ws_src[d2 * 4 + h];
    a_s[j][h] = s;
  } else if (tid < 132) {
    int h = tid - 128; float s = 0.f;
    for (int d2 = 0; d2 < 300; ++d2) s += xs[0][d2] * ws_dst[d2 * 4 + h];
    a_d0[h] = s;
  } else if (tid >= 192) {
    int e = tid - 192;
    int src = edge_index[g * 128 + e];
    int dst = edge_index[g * 128 + 64 + e];
    if (dst == 0) allowed[src] = 1;
  }
  __syncthreads();
  if (tid < 4) {
    int h = tid;
    float ev[32];
    float mx = -1e30f;
    #pragma unroll
    for (int j = 0; j < 32; ++j) {
      float v = a_d0[h] + a_s[j][h];
      v = (v > 0.f) ? v : 0.2f * v;
      v = allowed[j] ? v : -1e9f;
      ev[j] = v; mx = fmaxf(mx, v);
    }
    float ssum = 0.f;
    #pragma unroll
    for (int j = 0; j < 32; ++j) { float p = fexp(ev[j] - mx); ev[j] = p; ssum += p; }
    float inv = 1.f / ssum;
    #pragma unroll
    for (int j = 0; j < 32; ++j) alpha[h][j] = ev[j] * inv;
  }
  __syncthreads();
  for (int i = tid; i < 4 * 300; i += 256) {
    int h = i / 300, d2 = i - h * 300;
    float s = 0.f;
    #pragma unroll
    for (int j = 0; j < 32; ++j) s += alpha[h][j] * xs[j][d2];
    xw[h][d2] = s;
  }
  __syncthreads();
  int t = g % 35, b = g / 35;
  u16* srow = sig + ((size_t)t * 32 + b) * 640;
  for (int hc = tid; hc < 300; hc += 256) {
    srow[hc] = f2bf(xs[0][hc]);           // curr_emb = X[idx 0]
    int h = hc / 75;
    float s = gat_bias[hc];
    for (int d2 = 0; d2 < 300; ++d2) s += xw[h][d2] * gat_W[d2 * 300 + hc];
    srow[300 + hc] = f2bf(s);
  }
  for (int i2 = 600 + tid; i2 < 640; i2 += 256) srow[i2] = 0;  // zero pad
}

// ---------------- bulk input-gate GEMM (gll16 dbuf + swizzled LDS) ----------
// gates written INTERLEAVED: gates[m][u*4+g]  (one float4 per (m,unit))
__global__ void __launch_bounds__(256, 4) gemm_ig(
    const u16* __restrict__ A, const u16* __restrict__ Bw,
    float* __restrict__ gates, int K) {
  int bid = blockIdx.x;
  int bm = bid % 9, bn = bid / 9;
  int m0 = bm * 128, n0 = bn * 128;
  int tid = threadIdx.x, w = tid >> 6, lane = tid & 63, l15 = lane & 15, lhi = lane >> 4;
  int wm = w & 1, wn = w >> 1;
  __shared__ u16 As[2][128][32];
  __shared__ u16 Bs[2][128][32];
  int cl = ((lane & 3) ^ ((lane >> 3) & 3)) * 8;
  int am0 = m0 + w * 32 + (lane >> 2);
  int am1 = am0 + 16;
  const u16* arow0 = A + (size_t)((am0 < kM) ? am0 : 0) * K + cl;
  const u16* arow1 = A + (size_t)((am1 < kM) ? am1 : 0) * K + cl;
  int bn0r = n0 + w * 32 + (lane >> 2);
  const u16* brow0 = Bw + (size_t)bn0r * K + cl;
  const u16* brow1 = Bw + (size_t)(bn0r + 16) * K + cl;
  const int koff = (lhi ^ ((l15 >> 1) & 3)) * 8;  // read-side swizzle

  f32x4 acc[4][4];
  #pragma unroll
  for (int i = 0; i < 4; ++i)
    #pragma unroll
    for (int j = 0; j < 4; ++j) { f32x4 z = {0.f, 0.f, 0.f, 0.f}; acc[i][j] = z; }

  auto ISSUE = [&](int k0, int buf) {
    gll16(arow0 + k0, &As[buf][w * 32][0]);
    gll16(arow1 + k0, &As[buf][w * 32 + 16][0]);
    gll16(brow0 + k0, &Bs[buf][w * 32][0]);
    gll16(brow1 + k0, &Bs[buf][w * 32 + 16][0]);
  };
  int nkt = K >> 5;
  ISSUE(0, 0);
  for (int kt = 0; kt < nkt; ++kt) {
    int cur = kt & 1;
    if (kt < nkt - 1) {
      ISSUE((kt + 1) * 32, cur ^ 1);
      asm volatile("s_waitcnt vmcnt(4)" ::: "memory");
    } else {
      asm volatile("s_waitcnt vmcnt(0)" ::: "memory");
    }
    __builtin_amdgcn_s_barrier();
    __builtin_amdgcn_sched_barrier(0);
    short8 bfr[4];
    #pragma unroll
    for (int nt = 0; nt < 4; ++nt)
      bfr[nt] = *(const short8*)&Bs[cur][wn * 64 + nt * 16 + l15][koff];
    #pragma unroll
    for (int mt = 0; mt < 4; ++mt) {
      short8 af = *(const short8*)&As[cur][wm * 64 + mt * 16 + l15][koff];
      #pragma unroll
      for (int nt = 0; nt < 4; ++nt)
        acc[mt][nt] = mfma16(af, bfr[nt], acc[mt][nt]);
    }
    __builtin_amdgcn_sched_barrier(0);
    __builtin_amdgcn_s_barrier();
  }
  #pragma unroll
  for (int mt = 0; mt < 4; ++mt) {
    #pragma unroll
    for (int r = 0; r < 4; ++r) {
      int m = m0 + wm * 64 + mt * 16 + lhi * 4 + r;
      if (m < kM) {
        float* orow = gates + (size_t)m * 4096;
        #pragma unroll
        for (int nt = 0; nt < 4; ++nt) {
          int n = n0 + wn * 64 + nt * 16 + l15;
          orow[(n & 1023) * 4 + (n >> 10)] = acc[mt][nt][r];
        }
      }
    }
  }
}

// ---------------- fused 3-layer LSTM wavefront, wave-specialized ------------
// 256 blocks x 512 threads (8 waves). Block p owns units [4p,4p+4) for all
// layers. Jobs (wave pairs, K-halves 512):
//   w0-1: Whh0 x h0[s-1]        -> pred0
//   w2-3: Wih1 x h0[s-1]        -> pred1 (x-part)
//   w4-5: Whh1 x h1[s-2] -> pred1 (h-part); Wih2 x h1[s-2] -> pred2 (x-part)
//   w6-7: Whh2 x h2[s-3]        -> pred2 (h-part)
// All five matrix passes run CONCURRENTLY on different waves.
__global__ void __launch_bounds__(512, 1) lstm_fused012(
    const float* __restrict__ W_hh,      // [3][4096][1024]
    const float* __restrict__ W_ih_rest, // [2][4096][1024]
    const float* __restrict__ gates,     // [1120][1024][4] f32 (layer0 x-part)
    const float* __restrict__ bias_sum,  // [3][4096]
    u16* __restrict__ hist0, u16* __restrict__ hist1, u16* __restrict__ hist2,
    unsigned* __restrict__ flags) {
  const int p = blockIdx.x;            // 0..255
  const int u0 = p * 4;
  const int tid = threadIdx.x;
  const int w = tid >> 6, lane = tid & 63, l15 = lane & 15, lhi = lane >> 4;
  const int khalf = w & 1;
  const int job = w >> 1;              // 0:L0H 1:L1X 2:L1H+L2X 3:L2H
  const int kbase = khalf * 512;
  __shared__ float pred0[2][16][33];
  __shared__ float pred1[4][16][33];
  __shared__ float pred2[4][16][33];

  // prologue: weight fragments -> registers (fp32 -> bf16 inline)
  const int grow = (l15 >> 2) * 1024 + u0 + (l15 & 3);  // global weight row
  size_t rowoff = (size_t)grow * 1024 + kbase + lhi * 8;
  const float* m1;
  const float* m2 = W_ih_rest + (size_t)4096 * 1024 + rowoff;  // Wih2 (job2)
  if (job == 0)      m1 = W_hh + rowoff;
  else if (job == 1) m1 = W_ih_rest + rowoff;
  else if (job == 2) m1 = W_hh + (size_t)4096 * 1024 + rowoff;
  else               m1 = W_hh + (size_t)2 * 4096 * 1024 + rowoff;
  short8 r1[16], r2[16];
  #pragma unroll
  for (int kk = 0; kk < 16; ++kk) r1[kk] = ld8bf(m1 + kk * 32);
  if (job == 2) {
    #pragma unroll
    for (int kk = 0; kk < 16; ++kk) r2[kk] = ld8bf(m2 + kk * 32);
  }

  // pointwise roles: threads [0,128) layer0, [128,256) layer1, [256,384) layer2
  const int pw_layer = tid >> 7;       // 3 = none
  const int pb = (tid & 127) >> 2, pj = tid & 3;
  float bias_r[4] = {0.f, 0.f, 0.f, 0.f};
  if (pw_layer < 3) {
    #pragma unroll
    for (int g = 0; g < 4; ++g)
      bias_r[g] = bias_sum[pw_layer * 4096 + g * 1024 + u0 + pj];
  }
  float c_reg = 0.f;
  const unsigned* f0p = flags + khalf * 128 + lane;   // this wave's producers
  __syncthreads();

  for (int s = 0; s < 37; ++s) {
    bool active; const u16* hsrc;
    if (job == 0)      { active = (s >= 1 && s < 35);  hsrc = hist0 + (size_t)(s - 1) * 32 * 1024; }
    else if (job == 1) { active = (s >= 1 && s <= 35); hsrc = hist0 + (size_t)(s - 1) * 32 * 1024; }
    else if (job == 2) { active = (s >= 2 && s <= 36); hsrc = hist1 + (size_t)(s - 2) * 32 * 1024; }
    else               { active = (s >= 3 && s <= 36); hsrc = hist2 + (size_t)(s - 3) * 32 * 1024; }
    if (active) {
      unsigned tgt = (unsigned)s;
      while (!__all((int)((__hip_atomic_load(f0p, __ATOMIC_RELAXED,
                                             __HIP_MEMORY_SCOPE_AGENT) >= tgt) &
                          (__hip_atomic_load(f0p + 64, __ATOMIC_RELAXED,
                                             __HIP_MEMORY_SCOPE_AGENT) >= tgt))))
        __builtin_amdgcn_s_sleep(1);
      asm volatile("" ::: "memory");   // pin h loads behind the wait
    }
    f32x4 a0 = {0,0,0,0}, a1 = {0,0,0,0}, a2 = {0,0,0,0}, a3 = {0,0,0,0};
    if (active) {
      const u16* b0p = hsrc + l15 * 1024 + kbase + lhi * 8;
      const u16* b1p = hsrc + (l15 + 16) * 1024 + kbase + lhi * 8;
      if (job == 2) {
        #pragma unroll
        for (int kk = 0; kk < 16; ++kk) {
          short8 b0 = *(const short8*)(b0p + kk * 32);
          short8 b1 = *(const short8*)(b1p + kk * 32);
          a0 = mfma16(r1[kk], b0, a0);
          a1 = mfma16(r1[kk], b1, a1);
          a2 = mfma16(r2[kk], b0, a2);
          a3 = mfma16(r2[kk], b1, a3);
        }
      } else {
        #pragma unroll
        for (int kk = 0; kk < 16; ++kk) {
          short8 b0 = *(const short8*)(b0p + kk * 32);
          short8 b1 = *(const short8*)(b1p + kk * 32);
          a0 = mfma16(r1[kk], b0, a0);
          a1 = mfma16(r1[kk], b1, a1);
        }
      }
    }
    #pragma unroll
    for (int r = 0; r < 4; ++r) {
      int row = lhi * 4 + r;
      if (job == 0) {
        pred0[khalf][row][l15] = a0[r];      pred0[khalf][row][l15 + 16] = a1[r];
      } else if (job == 1) {
        pred1[khalf][row][l15] = a0[r];      pred1[khalf][row][l15 + 16] = a1[r];
      } else if (job == 2) {
        pred1[2 + khalf][row][l15] = a0[r];  pred1[2 + khalf][row][l15 + 16] = a1[r];
        pred2[khalf][row][l15] = a2[r];      pred2[khalf][row][l15 + 16] = a3[r];
      } else {
        pred2[2 + khalf][row][l15] = a0[r];  pred2[2 + khalf][row][l15 + 16] = a1[r];
      }
    }
    __syncthreads();
    bool act = (pw_layer == 0) ? (s < 35)
             : (pw_layer == 1) ? (s >= 1 && s <= 35)
             : (pw_layer == 2) ? (s >= 2 && s <= 36) : false;
    if (act) {
      float pre[4];
      if (pw_layer == 0) {
        #pragma unroll
        for (int g = 0; g < 4; ++g) {
          int row = g * 4 + pj;
          pre[g] = pred0[0][row][pb] + pred0[1][row][pb];
        }
        float4 gx = ((const float4*)gates)[(size_t)(s * 32 + pb) * 1024 + u0 + pj];
        pre[0] += gx.x; pre[1] += gx.y; pre[2] += gx.z; pre[3] += gx.w;
      } else if (pw_layer == 1) {
        #pragma unroll
        for (int g = 0; g < 4; ++g) {
          int row = g * 4 + pj;
          pre[g] = pred1[0][row][pb] + pred1[1][row][pb] +
                   pred1[2][row][pb] + pred1[3][row][pb];
        }
      } else {
        #pragma unroll
        for (int g = 0; g < 4; ++g) {
          int row = g * 4 + pj;
          pre[g] = pred2[0][row][pb] + pred2[1][row][pb] +
                   pred2[2][row][pb] + pred2[3][row][pb];
        }
      }
      float iv = pre[0] + bias_r[0];
      float fv = pre[1] + bias_r[1];
      float gv = pre[2] + bias_r[2];
      float ov = pre[3] + bias_r[3];
      float cc = fsigm(fv) * c_reg + fsigm(iv) * ftanh(gv);
      float hh = fsigm(ov) * ftanh(cc);
      c_reg = cc;
      int t = s - pw_layer;
      u16* dst = (pw_layer == 0) ? hist0 : (pw_layer == 1) ? hist1 : hist2;
      store_u16_llc(dst + ((size_t)(t * 32 + pb) << 10) + u0 + pj, f2bf(hh));
    }
    __syncthreads();   // drains LLC stores (per-wave vmcnt 0) + pred reuse
    if (s < 36 && tid == 0)
      __hip_atomic_store(flags + p, (unsigned)(s + 1),
                         __ATOMIC_RELAXED, __HIP_MEMORY_SCOPE_AGENT);
  }
}

// ---------------- logits GEMM epilogue --------------------------------------
DEV void logits_epilogue(f32x4 (&acc)[4][4], int m0, int n0, int wm, int wn,
                         int l15, int lhi, const float* lin_b,
                         float* out, float2* partials, int bn) {
  float bcol[4]; int ncol[4];
  #pragma unroll
  for (int nt = 0; nt < 4; ++nt) {
    int n = n0 + wn * 64 + nt * 16 + l15;
    ncol[nt] = n;
    bcol[nt] = (n < kVG) ? lin_b[n] : -INFINITY;
  }
  #pragma unroll
  for (int mt = 0; mt < 4; ++mt) {
    #pragma unroll
    for (int r = 0; r < 4; ++r) {
      int m = m0 + wm * 64 + mt * 16 + lhi * 4 + r;
      float v0 = acc[mt][0][r] + bcol[0];
      float v1 = acc[mt][1][r] + bcol[1];
      float v2 = acc[mt][2][r] + bcol[2];
      float v3 = acc[mt][3][r] + bcol[3];
      bool mok = (m < kM);
      if (mok) {
        float* orow = out + (size_t)m * kVG;
        if (ncol[0] < kVG) orow[ncol[0]] = v0;
        if (ncol[1] < kVG) orow[ncol[1]] = v1;
        if (ncol[2] < kVG) orow[ncol[2]] = v2;
        if (ncol[3] < kVG) orow[ncol[3]] = v3;
      }
      float mx = fmaxf(fmaxf(v0, v1), fmaxf(v2, v3));
      #pragma unroll
      for (int d2 = 1; d2 < 16; d2 <<= 1) mx = fmaxf(mx, __shfl_xor(mx, d2, 64));
      float sv = 0.f;
      sv += (v0 > -1e30f) ? fexp(v0 - mx) : 0.f;
      sv += (v1 > -1e30f) ? fexp(v1 - mx) : 0.f;
      sv += (v2 > -1e30f) ? fexp(v2 - mx) : 0.f;
      sv += (v3 > -1e30f) ? fexp(v3 - mx) : 0.f;
      #pragma unroll
      for (int d2 = 1; d2 < 16; d2 <<= 1) sv += __shfl_xor(sv, d2, 64);
      if (mok && l15 == 0)
        partials[(size_t)m * 784 + bn * 2 + wn] = make_float2(mx, sv);
    }
  }
}

// ---------------- logits GEMM (gll16 dbuf + swizzled LDS) -------------------
__global__ void __launch_bounds__(256, 4) gemm_logits_async(
    const u16* __restrict__ hist2, const u16* __restrict__ linwb,
    const float* __restrict__ lin_b, float* __restrict__ out,
    float2* __restrict__ partials) {
  int nwg = gridDim.x, orig = blockIdx.x;
  int q = nwg >> 3, r = nwg & 7, xcd = orig & 7, off = orig >> 3;
  int bid = (xcd < r ? xcd * (q + 1) : r * (q + 1) + (xcd - r) * q) + off;
  int bm = bid % 9, bn = bid / 9;
  int m0 = bm * 128, n0 = bn * 128;
  int tid = threadIdx.x, w = tid >> 6, lane = tid & 63, l15 = lane & 15, lhi = lane >> 4;
  int wm = w & 1, wn = w >> 1;
  __shared__ u16 As[2][128][32];
  __shared__ u16 Bs[2][128][32];
  int cl = ((lane & 3) ^ ((lane >> 3) & 3)) * 8;
  int am0 = m0 + w * 32 + (lane >> 2);
  int am1 = am0 + 16;
  int mm0 = (am0 < kM) ? am0 : 0, mm1 = (am1 < kM) ? am1 : 0;
  const u16* arow0 = hist2 + (((size_t)((mm0 % 35) * 32 + mm0 / 35)) << 10) + cl;
  const u16* arow1 = hist2 + (((size_t)((mm1 % 35) * 32 + mm1 / 35)) << 10) + cl;
  int nr0 = n0 + w * 32 + (lane >> 2);
  int nn0 = (nr0 < kVG) ? nr0 : 0, nn1 = (nr0 + 16 < kVG) ? nr0 + 16 : 0;
  const u16* brow0 = linwb + ((size_t)nn0 << 10) + cl;
  const u16* brow1 = linwb + ((size_t)nn1 << 10) + cl;
  const int koff = (lhi ^ ((l15 >> 1) & 3)) * 8;

  f32x4 acc[4][4];
  #pragma unroll
  for (int i = 0; i < 4; ++i)
    #pragma unroll
    for (int j = 0; j < 4; ++j) { f32x4 z = {0.f, 0.f, 0.f, 0.f}; acc[i][j] = z; }

  auto ISSUE = [&](int k0, int buf) {
    gll16(arow0 + k0, &As[buf][w * 32][0]);
    gll16(arow1 + k0, &As[buf][w * 32 + 16][0]);
    gll16(brow0 + k0, &Bs[buf][w * 32][0]);
    gll16(brow1 + k0, &Bs[buf][w * 32 + 16][0]);
  };
  ISSUE(0, 0);
  for (int kt = 0; kt < 32; ++kt) {
    int cur = kt & 1;
    if (kt < 31) {
      ISSUE((kt + 1) * 32, cur ^ 1);
      asm volatile("s_waitcnt vmcnt(4)" ::: "memory");
    } else {
      asm volatile("s_waitcnt vmcnt(0)" ::: "memory");
    }
    __builtin_amdgcn_s_barrier();
    __builtin_amdgcn_sched_barrier(0);
    short8 bfr[4];
    #pragma unroll
    for (int nt = 0; nt < 4; ++nt)
      bfr[nt] = *(const short8*)&Bs[cur][wn * 64 + nt * 16 + l15][koff];
    #pragma unroll
    for (int mt = 0; mt < 4; ++mt) {
      short8 af = *(const short8*)&As[cur][wm * 64 + mt * 16 + l15][koff];
      #pragma unroll
      for (int nt = 0; nt < 4; ++nt)
        acc[mt][nt] = mfma16(af, bfr[nt], acc[mt][nt]);
    }
    __builtin_amdgcn_sched_barrier(0);
    __builtin_amdgcn_s_barrier();
  }
  logits_epilogue(acc, m0, n0, wm, wn, l15, lhi, lin_b, out, partials, bn);
}

// fallback (no bf16 workspace image): reg-staged, fp32 B inline-converted
__global__ void __launch_bounds__(256, 1) gemm_logits_fb(
    const u16* __restrict__ hist2, const float* __restrict__ lin_W,
    const float* __restrict__ lin_b, float* __restrict__ out,
    float2* __restrict__ partials) {
  int nwg = gridDim.x, orig = blockIdx.x;
  int q = nwg >> 3, r = nwg & 7, xcd = orig & 7, off = orig >> 3;
  int bid = (xcd < r ? xcd * (q + 1) : r * (q + 1) + (xcd - r) * q) + off;
  int bm = bid % 9, bn = bid / 9;
  int m0 = bm * 128, n0 = bn * 128;
  int tid = threadIdx.x, w = tid >> 6, lane = tid & 63, l15 = lane & 15, lhi = lane >> 4;
  int wm = w & 1, wn = w >> 1;
  __shared__ u16 As[128][40];
  __shared__ u16 Bs[128][40];
  f32x4 acc[4][4];
  #pragma unroll
  for (int i = 0; i < 4; ++i)
    #pragma unroll
    for (int j = 0; j < 4; ++j) { f32x4 z = {0.f, 0.f, 0.f, 0.f}; acc[i][j] = z; }
  for (int kt = 0; kt < 32; ++kt) {
    int k0 = kt * 32;
    #pragma unroll
    for (int q2 = 0; q2 < 2; ++q2) {
      int c = tid * 2 + q2; int row = c >> 2; int ch = c & 3;
      int m = m0 + row;
      uint4 av{0u, 0u, 0u, 0u};
      if (m < kM) {
        int b = m / 35; int t = m - b * 35;
        av = *(const uint4*)(hist2 + ((size_t)(t * 32 + b) << 10) + k0 + ch * 8);
      }
      *(uint4*)&As[row][ch * 8] = av;
      int n = n0 + row;
      uint4 bv{0u, 0u, 0u, 0u};
      if (n < kVG) {
        const float* src = lin_W + (size_t)n * 1024 + k0 + ch * 8;
        float4 f0 = *(const float4*)(src);
        float4 f1 = *(const float4*)(src + 4);
        bv.x = (unsigned)f2bf(f0.x) | ((unsigned)f2bf(f0.y) << 16);
        bv.y = (unsigned)f2bf(f0.z) | ((unsigned)f2bf(f0.w) << 16);
        bv.z = (unsigned)f2bf(f1.x) | ((unsigned)f2bf(f1.y) << 16);
        bv.w = (unsigned)f2bf(f1.z) | ((unsigned)f2bf(f1.w) << 16);
      }
      *(uint4*)&Bs[row][ch * 8] = bv;
    }
    __syncthreads();
    short8 bfr[4];
    #pragma unroll
    for (int nt = 0; nt < 4; ++nt)
      bfr[nt] = *(const short8*)&Bs[wn * 64 + nt * 16 + l15][lhi * 8];
    #pragma unroll
    for (int mt = 0; mt < 4; ++mt) {
      short8 af = *(const short8*)&As[wm * 64 + mt * 16 + l15][lhi * 8];
      #pragma unroll
      for (int nt = 0; nt < 4; ++nt)
        acc[mt][nt] = mfma16(af, bfr[nt], acc[mt][nt]);
    }
    __syncthreads();
  }
  logits_epilogue(acc, m0, n0, wm, wn, l15, lhi, lin_b, out, partials, bn);
}

// ---------------- row logsumexp reduce --------------------------------------
__global__ void reduce_rows(const float2* __restrict__ partials, float* __restrict__ lse) {
  int m = blockIdx.x, tid = threadIdx.x;
  float mx = -INFINITY, s = 0.f;
  for (int j = tid; j < 782; j += 256) {
    float2 p = partials[(size_t)m * 784 + j];
    if (p.x > mx) { s = s * fexp(mx - p.x) + p.y; mx = p.x; }
    else          { s += p.y * fexp(p.x - mx); }
  }
  for (int d = 1; d < 64; d <<= 1) {
    float omx = __shfl_xor(mx, d, 64);
    float os  = __shfl_xor(s, d, 64);
    if (omx > mx) { s = s * fexp(mx - omx) + os; mx = omx; }
    else          { s += os * fexp(omx - mx); }
  }
  __shared__ float smx[4], ssum[4];
  int w = tid >> 6;
  if ((tid & 63) == 0) { smx[w] = mx; ssum[w] = s; }
  __syncthreads();
  if (tid == 0) {
    for (int i = 1; i < 4; ++i) {
      float omx = smx[i], os = ssum[i];
      if (omx > mx) { s = s * fexp(mx - omx) + os; mx = omx; }
      else          { s += os * fexp(omx - mx); }
    }
    lse[m] = mx + logf(s);
  }
}

// ---------------- in-place log_softmax subtract -----------------------------
__global__ void sub_lse(float* __restrict__ out, const float* __restrict__ lse) {
  const int total4 = 14000000;  // 1120*50000/4
  for (int i = blockIdx.x * blockDim.x + threadIdx.x; i < total4; i += gridDim.x * blockDim.x) {
    int m = i / 12500;
    float4 v = ((float4*)out)[i];
    float L = lse[m];
    v.x -= L; v.y -= L; v.z -= L; v.w -= L;
    ((float4*)out)[i] = v;
  }
}

// ---------------- launch ----------------------------------------------------
extern "C" void kernel_launch(void* const* d_in, const int* in_sizes, int n_in,
                              void* d_out, int out_size, void* d_ws, size_t ws_size,
                              hipStream_t stream) {
  const int*   x_indices  = (const int*)d_in[0];
  const int*   edge_index = (const int*)d_in[1];
  const float* X          = (const float*)d_in[2];
  const float* gat_W      = (const float*)d_in[3];
  const float* att_src    = (const float*)d_in[4];
  const float* att_dst    = (const float*)d_in[5];
  const float* gat_bias   = (const float*)d_in[6];
  const float* W_ih0      = (const float*)d_in[7];
  const float* W_ih_rest  = (const float*)d_in[8];
  const float* W_hh       = (const float*)d_in[9];
  const float* b_ih       = (const float*)d_in[10];
  const float* b_hh       = (const float*)d_in[11];
  const float* lin_W      = (const float*)d_in[12];
  const float* lin_b      = (const float*)d_in[13];
  float* out = (float*)d_out;
  char* ws = (char*)d_ws;

  unsigned* flags    = (unsigned*)(ws + OFF_BAR);
  float*    ws_src   = (float*)(ws + OFF_WSRC);
  float*    ws_dst   = (float*)(ws + OFF_WDST);
  float*    bias_sum = (float*)(ws + OFF_BIAS);
  u16*      sig      = (u16*)(ws + OFF_SIG);
  u16*      wx0      = (u16*)(ws + OFF_WX0);
  float*    gates    = (float*)(ws + OFF_GATES);
  u16*      hist     = (u16*)(ws + OFF_HIST);
  float2*   partials = (float2*)(ws + OFF_PART);
  float*    lse      = (float*)(ws + OFF_LSE);
  u16*      linwb    = (u16*)(ws + OFF_LINWB);
  bool use_bw = (ws_size >= kNeedBW);

  u16* hist0 = hist;
  u16* hist1 = hist + (size_t)35 * 32 * 1024;
  u16* hist2 = hist + (size_t)2 * 35 * 32 * 1024;

  hipMemsetAsync(ws + OFF_BAR, 0, 1024, stream);
  prep_small<<<64, 256, 0, stream>>>(gat_W, att_src, att_dst, b_ih, b_hh,
                                     ws_src, ws_dst, bias_sum);
  wx_prep<<<512, 256, 0, stream>>>(W_ih0, wx0);
  if (use_bw) wb_conv<<<2048, 256, 0, stream>>>(lin_W, linwb);
  gat_kernel<<<kG, 256, 0, stream>>>(x_indices, edge_index, X, gat_W, gat_bias,
                                     ws_src, ws_dst, sig);
  // layer 0 input transform (bulk)
  gemm_ig<<<288, 256, 0, stream>>>(sig, wx0, gates, 640);
  // fused 3-layer wavefront (37 supersteps, wave-specialized, dataflow flags)
  lstm_fused012<<<256, 512, 0, stream>>>(W_hh, W_ih_rest, gates, bias_sum,
                                         hist0, hist1, hist2, flags);
  // logits + log_softmax
  if (use_bw)
    gemm_logits_async<<<9 * 391, 256, 0, stream>>>(hist2, linwb, lin_b, out, partials);
  else
    gemm_logits_fb<<<9 * 391, 256, 0, stream>>>(hist2, lin_W, lin_b, out, partials);
  reduce_rows<<<kG, 256, 0, stream>>>(partials, lse);
  sub_lse<<<2048, 256, 0, stream>>>(out, lse);
}